// Round 6
// baseline (1276.220 us; speedup 1.0000x reference)
//
#include <hip/hip_runtime.h>
#include <cstddef>

#define NN 50000
#define EE 400000
#define BB 64
#define MP 50048            // padded rows: 391 * 128
#define BN_EPS 1e-5f

typedef __attribute__((ext_vector_type(8))) short s16x8;
typedef __attribute__((ext_vector_type(4))) float f32x4;

#define GLOAD_LDS16(g, l) __builtin_amdgcn_global_load_lds( \
    (const __attribute__((address_space(1))) void*)(g),     \
    (__attribute__((address_space(3))) void*)(l), 16, 0, 0)

// ---------------- utility ----------------
__global__ void fill_f32(float* __restrict__ p, int n, float v) {
    int i = blockIdx.x * blockDim.x + threadIdx.x;
    if (i < n) p[i] = v;
}

__global__ void fill_i32(int* __restrict__ p, int n, int v) {
    int i = blockIdx.x * blockDim.x + threadIdx.x;
    if (i < n) p[i] = v;
}

__global__ void deg_edges(const int* __restrict__ ei, int* __restrict__ deg) {
    int e = blockIdx.x * blockDim.x + threadIdx.x;
    if (e < EE) atomicAdd(&deg[ei[EE + e]], 1);
}

__global__ void rsqrt_k(const int* __restrict__ deg, float* __restrict__ dis) {
    int i = blockIdx.x * blockDim.x + threadIdx.x;
    if (i < NN) dis[i] = rsqrtf((float)deg[i] + 1.0f);
}

// W [K][N] fp32 -> two bf16 planes Wh/Wl [N][K] (hi = truncate, lo = residual)
__global__ void cvt_wt_planes(const float* __restrict__ W,
                              unsigned short* __restrict__ Wh,
                              unsigned short* __restrict__ Wl,
                              int K, int N) {
    int i = blockIdx.x * blockDim.x + threadIdx.x;
    if (i >= K * N) return;
    int k = i / N, n = i % N;
    float f = W[i];
    unsigned int fb = __float_as_uint(f);
    unsigned int hif = fb & 0xFFFF0000u;
    float lo = f - __uint_as_float(hif);
    Wh[(size_t)n * K + k] = (unsigned short)(hif >> 16);
    Wl[(size_t)n * K + k] = (unsigned short)(__float_as_uint(lo) >> 16);
}

// ---------------- CSR build ----------------
__global__ __launch_bounds__(256) void scan_block(const int* __restrict__ deg,
                                                  int* __restrict__ rowptr,
                                                  int* __restrict__ bsum) {
    __shared__ int tmp[256];
    int tid = threadIdx.x;
    int i = blockIdx.x * 256 + tid;
    int v = (i < NN) ? deg[i] : 0;
    tmp[tid] = v;
    __syncthreads();
#pragma unroll
    for (int off = 1; off < 256; off <<= 1) {
        int t = (tid >= off) ? tmp[tid - off] : 0;
        __syncthreads();
        tmp[tid] += t;
        __syncthreads();
    }
    if (i < NN) rowptr[i] = tmp[tid] - v;
    if (tid == 255) bsum[blockIdx.x] = tmp[255];
}

__global__ __launch_bounds__(256) void scan_sums(const int* __restrict__ bsum,
                                                 int* __restrict__ boff, int nb) {
    __shared__ int tmp[256];
    int tid = threadIdx.x;
    int v = (tid < nb) ? bsum[tid] : 0;
    tmp[tid] = v;
    __syncthreads();
#pragma unroll
    for (int off = 1; off < 256; off <<= 1) {
        int t = (tid >= off) ? tmp[tid - off] : 0;
        __syncthreads();
        tmp[tid] += t;
        __syncthreads();
    }
    boff[tid] = tmp[tid] - v;
}

__global__ void scan_fixup(int* __restrict__ rowptr, const int* __restrict__ boff) {
    int i = blockIdx.x * blockDim.x + threadIdx.x;
    if (i < NN) rowptr[i] += boff[i >> 8];
    if (i == 0) rowptr[NN] = EE;
}

__global__ void copy_i32(const int* __restrict__ a, int* __restrict__ b, int n) {
    int i = blockIdx.x * blockDim.x + threadIdx.x;
    if (i < n) b[i] = a[i];
}

__global__ void fill_csr(const int* __restrict__ ei, int* __restrict__ cursor,
                         int* __restrict__ csr_src) {
    int e = blockIdx.x * blockDim.x + threadIdx.x;
    if (e >= EE) return;
    int s = ei[e];
    int t = ei[EE + e];
    int pos = atomicAdd(&cursor[t], 1);
    csr_src[pos] = s;
}

// ---------------- split helpers (mask/shift only — hardware-validated r5) -------
// packed u32 p = (hi bf16 bits << 16) | (lo bf16 bits)
static __device__ __forceinline__ void unpack_pk(const uint4& u0, const uint4& u1,
                                                 s16x8& h, s16x8& l) {
    unsigned int p[8] = {u0.x, u0.y, u0.z, u0.w, u1.x, u1.y, u1.z, u1.w};
    union { s16x8 v; unsigned int u[4]; } H, L;
#pragma unroll
    for (int k = 0; k < 4; ++k) {
        H.u[k] = (p[2 * k + 1] & 0xFFFF0000u) | (p[2 * k] >> 16);
        L.u[k] = (p[2 * k + 1] << 16) | (p[2 * k] & 0xFFFFu);
    }
    h = H.v; l = L.v;
}

// 8 consecutive fp32 -> hi bf16 (truncate) + lo bf16 (residual)
static __device__ __forceinline__ void unpack_f32(const uint4& u0, const uint4& u1,
                                                  s16x8& h, s16x8& l) {
    unsigned int e[8] = {u0.x, u0.y, u0.z, u0.w, u1.x, u1.y, u1.z, u1.w};
    unsigned int hi[8], lo[8];
#pragma unroll
    for (int j = 0; j < 8; ++j) {
        hi[j] = e[j] & 0xFFFF0000u;
        float lf = __uint_as_float(e[j]) - __uint_as_float(hi[j]);
        lo[j] = __float_as_uint(lf);
    }
    union { s16x8 v; unsigned int u[4]; } H, L;
#pragma unroll
    for (int k = 0; k < 4; ++k) {
        H.u[k] = (hi[2 * k + 1]) | (hi[2 * k] >> 16);
        L.u[k] = (lo[2 * k + 1] & 0xFFFF0000u) | (lo[2 * k] >> 16);
    }
    h = H.v; l = L.v;
}

// ------ split-bf16 3-MFMA GEMM: C[MP,N] = A[MP,K] @ W[N,K]^T, fp32 out ------
// B pre-split into bf16 planes Wh/Wl (zero B-unpack). AMODE 0: A fp32 (in-kernel
// split). AMODE 1: A packed u32 (mask/shift unpack). 128x128 tile, BK=32, 4 waves.
template <int AMODE>
__global__ __launch_bounds__(256) void gemm_split3(const unsigned int* __restrict__ A,
                                                   const unsigned short* __restrict__ Bh,
                                                   const unsigned short* __restrict__ Bl,
                                                   float* __restrict__ C,
                                                   int K, int N) {
    __shared__ unsigned int As[128 * 32];     // 16 KB  [row][k-u32]
    __shared__ unsigned short Bsh[128 * 32];  // 8 KB   [col][k]
    __shared__ unsigned short Bsl[128 * 32];  // 8 KB
    const int tid = threadIdx.x;
    const int w  = tid >> 6;
    const int lw = tid & 63;
    const int lo = lw & 15;
    const int hi = lw >> 4;
    const int wr = w >> 1, wc = w & 1;
    const int rowBase = blockIdx.y * 128;
    const int colBase = blockIdx.x * 128;

    const int arow = w * 8 + (lw >> 3);       // A staging: 8 rows/instr
    const int acol = (lw & 7) * 4;            // u32 col
    const int brow = w * 16 + (lw >> 2);      // B staging: 16 rows/instr
    const int bcol = (lw & 3) * 8;            // bf16 col

    f32x4 acc[4][4];
#pragma unroll
    for (int m = 0; m < 4; ++m)
#pragma unroll
        for (int n = 0; n < 4; ++n) acc[m][n] = (f32x4){0.f, 0.f, 0.f, 0.f};

    for (int k0 = 0; k0 < K; k0 += 32) {
#pragma unroll
        for (int i = 0; i < 4; ++i) {
            int gr = rowBase + i * 32 + arow;
            gr = (gr < NN) ? gr : (NN - 1);
            GLOAD_LDS16(A + (size_t)gr * K + k0 + acol, (char*)As + i * 4096 + w * 1024);
        }
#pragma unroll
        for (int j = 0; j < 2; ++j) {
            int gc = colBase + j * 64 + brow;
            GLOAD_LDS16(Bh + (size_t)gc * K + k0 + bcol, (char*)Bsh + j * 4096 + w * 1024);
            GLOAD_LDS16(Bl + (size_t)gc * K + k0 + bcol, (char*)Bsl + j * 4096 + w * 1024);
        }
        __syncthreads();

        s16x8 ah[4], al[4], bh[4], bl[4];
#pragma unroll
        for (int m = 0; m < 4; ++m) {
            int r = wr * 64 + m * 16 + lo;
            uint4 u0 = *(const uint4*)&As[r * 32 + hi * 8];
            uint4 u1 = *(const uint4*)&As[r * 32 + hi * 8 + 4];
            if (AMODE == 0) unpack_f32(u0, u1, ah[m], al[m]);
            else            unpack_pk(u0, u1, ah[m], al[m]);
        }
#pragma unroll
        for (int n = 0; n < 4; ++n) {
            int r = wc * 64 + n * 16 + lo;
            bh[n] = *(const s16x8*)&Bsh[r * 32 + hi * 8];
            bl[n] = *(const s16x8*)&Bsl[r * 32 + hi * 8];
        }
#pragma unroll
        for (int m = 0; m < 4; ++m)
#pragma unroll
            for (int n = 0; n < 4; ++n) {
                acc[m][n] = __builtin_amdgcn_mfma_f32_16x16x32_bf16(ah[m], bh[n], acc[m][n], 0, 0, 0);
                acc[m][n] = __builtin_amdgcn_mfma_f32_16x16x32_bf16(ah[m], bl[n], acc[m][n], 0, 0, 0);
                acc[m][n] = __builtin_amdgcn_mfma_f32_16x16x32_bf16(al[m], bh[n], acc[m][n], 0, 0, 0);
            }
        __syncthreads();
    }

#pragma unroll
    for (int m = 0; m < 4; ++m) {
        int row0 = rowBase + wr * 64 + m * 16 + hi * 4;
#pragma unroll
        for (int n = 0; n < 4; ++n) {
            int col = colBase + wc * 64 + n * 16 + lo;
#pragma unroll
            for (int j = 0; j < 4; ++j)
                C[(size_t)(row0 + j) * N + col] = acc[m][n][j];
        }
    }
}

// ------ gather aggregation + fused BN stats (no atomics on features) ------
// Block owns a 64-node stripe; per-thread partial sum/sumsq; LDS reduce;
// one atomicAdd per channel per block into stats[0:D]=sum, stats[D:2D]=sumsq.
__global__ __launch_bounds__(256) void agg_gather_st(const float* __restrict__ hw,
                                                     float* __restrict__ agg,
                                                     const int* __restrict__ rowptr,
                                                     const int* __restrict__ csr_src,
                                                     const float* __restrict__ dis,
                                                     const float* __restrict__ bias,
                                                     float* __restrict__ stats,
                                                     int D) {
    const int tpn = D >> 2;                 // threads per node (float4 each)
    const int npb = 256 / tpn;              // node-lanes per block
    const int local = threadIdx.x / tpn;
    const int lane = threadIdx.x % tpn;
    const int dq = lane * 4;
    const float4 bsv = *reinterpret_cast<const float4*>(&bias[dq]);

    float s0 = 0.f, s1 = 0.f, s2 = 0.f, s3 = 0.f;
    float q0 = 0.f, q1 = 0.f, q2 = 0.f, q3 = 0.f;

    for (int i = local; i < 64; i += npb) {
        int n = blockIdx.x * 64 + i;
        if (n >= NN) break;
        float din = dis[n];
        float w0 = din * din;
        float4 self = *reinterpret_cast<const float4*>(&hw[(size_t)n * D + dq]);
        float4 acc;
        acc.x = w0 * self.x + bsv.x;
        acc.y = w0 * self.y + bsv.y;
        acc.z = w0 * self.z + bsv.z;
        acc.w = w0 * self.w + bsv.w;

        int e0 = rowptr[n], e1 = rowptr[n + 1];
        for (int e = e0; e < e1; ++e) {
            int s = csr_src[e];
            float ww = din * dis[s];
            float4 v = *reinterpret_cast<const float4*>(&hw[(size_t)s * D + dq]);
            acc.x += ww * v.x;
            acc.y += ww * v.y;
            acc.z += ww * v.z;
            acc.w += ww * v.w;
        }
        *reinterpret_cast<float4*>(&agg[(size_t)n * D + dq]) = acc;
        s0 += acc.x; s1 += acc.y; s2 += acc.z; s3 += acc.w;
        q0 += acc.x * acc.x; q1 += acc.y * acc.y;
        q2 += acc.z * acc.z; q3 += acc.w * acc.w;
    }

    __shared__ float red_s[1024];
    __shared__ float red_q[1024];
    int t4 = threadIdx.x * 4;
    red_s[t4 + 0] = s0; red_s[t4 + 1] = s1; red_s[t4 + 2] = s2; red_s[t4 + 3] = s3;
    red_q[t4 + 0] = q0; red_q[t4 + 1] = q1; red_q[t4 + 2] = q2; red_q[t4 + 3] = q3;
    __syncthreads();

    if (local == 0) {
        for (int g = 1; g < npb; ++g) {
            int t = (g * tpn + lane) * 4;
            s0 += red_s[t + 0]; s1 += red_s[t + 1]; s2 += red_s[t + 2]; s3 += red_s[t + 3];
            q0 += red_q[t + 0]; q1 += red_q[t + 1]; q2 += red_q[t + 2]; q3 += red_q[t + 3];
        }
        atomicAdd(&stats[dq + 0], s0); atomicAdd(&stats[dq + 1], s1);
        atomicAdd(&stats[dq + 2], s2); atomicAdd(&stats[dq + 3], s3);
        atomicAdd(&stats[D + dq + 0], q0); atomicAdd(&stats[D + dq + 1], q1);
        atomicAdd(&stats[D + dq + 2], q2); atomicAdd(&stats[D + dq + 3], q3);
    }
}

// ---------------- batchnorm apply (fp32 in-place; optional split-pack out) -------
__global__ void bn_apply(unsigned int* __restrict__ buf,
                         const float* __restrict__ stats,
                         const float* __restrict__ gamma, const float* __restrict__ beta,
                         int D, int do_relu, int do_pack) {
    size_t i = (size_t)blockIdx.x * blockDim.x + threadIdx.x;
    if (i >= (size_t)NN * D) return;
    int d = (int)(i % (size_t)D);
    float mean = stats[d] * (1.0f / NN);
    float var  = stats[D + d] * (1.0f / NN) - mean * mean;
    float f = (__uint_as_float(buf[i]) - mean) * rsqrtf(var + BN_EPS) * gamma[d] + beta[d];
    if (do_relu) f = fmaxf(f, 0.f);
    if (do_pack) {
        unsigned int fb = __float_as_uint(f);
        unsigned int hif = fb & 0xFFFF0000u;
        float lf = f - __uint_as_float(hif);
        buf[i] = hif | (__float_as_uint(lf) >> 16);
    } else {
        buf[i] = __float_as_uint(f);
    }
}

// ---------------- pooling ----------------
__global__ void find_starts(const int* __restrict__ batch, int* __restrict__ start) {
    int n = blockIdx.x * blockDim.x + threadIdx.x;
    if (n >= NN) return;
    int bc = batch[n];
    int bp = (n == 0) ? -1 : batch[n - 1];
    for (int g = bp + 1; g <= bc; ++g) start[g] = n;
    if (n == NN - 1) {
        for (int g = bc + 1; g <= BB; ++g) start[g] = NN;
    }
}

__global__ void pool_kernel(const float* __restrict__ h, const int* __restrict__ start,
                            float* __restrict__ pool) {
    int b = blockIdx.x;
    int d = threadIdx.x;
    int s0 = start[b], s1 = start[b + 1];
    float sum = 0.f;
    float mx = -3.402823466e+38f;
    for (int n = s0; n < s1; ++n) {
        float v = h[(size_t)n * 128 + d];
        sum += v;
        mx = fmaxf(mx, v);
    }
    float cnt = fmaxf((float)(s1 - s0), 1.0f);
    pool[b * 256 + d] = sum / cnt;
    pool[b * 256 + 128 + d] = mx;
}

// ---------------- classifier (single block, fp32) ----------------
__global__ __launch_bounds__(256) void classifier_kernel(
        const float* __restrict__ pool,
        const float* __restrict__ Wc1, const float* __restrict__ bc1,
        const float* __restrict__ gc, const float* __restrict__ bec,
        const float* __restrict__ Wc2, const float* __restrict__ bc2,
        float* __restrict__ out) {
    __shared__ float hc[64][65];
    __shared__ float cmean[64];
    __shared__ float crstd[64];
    int tid = threadIdx.x;

    for (int i = tid; i < 64 * 64; i += 256) {
        int r = i / 64, c = i % 64;
        float acc = bc1[c];
        for (int k = 0; k < 256; ++k)
            acc += pool[r * 256 + k] * Wc1[k * 64 + c];
        hc[r][c] = fmaxf(acc, 0.f);
    }
    __syncthreads();

    if (tid < 64) {
        float s = 0.f, ss = 0.f;
        for (int r = 0; r < 64; ++r) {
            float v = hc[r][tid];
            s += v;
            ss += v * v;
        }
        float m = s * (1.0f / 64.0f);
        float var = ss * (1.0f / 64.0f) - m * m;
        cmean[tid] = m;
        crstd[tid] = rsqrtf(var + BN_EPS);
    }
    __syncthreads();

    if (tid < 128) {
        int r = tid / 2, k = tid % 2;
        float acc = bc2[k];
        for (int c = 0; c < 64; ++c) {
            float v = (hc[r][c] - cmean[c]) * crstd[c] * gc[c] + bec[c];
            acc += v * Wc2[c * 2 + k];
        }
        out[r * 2 + k] = acc;
    }
}

// ---------------- launch ----------------
extern "C" void kernel_launch(void* const* d_in, const int* in_sizes, int n_in,
                              void* d_out, int out_size, void* d_ws, size_t ws_size,
                              hipStream_t stream) {
    const float* x     = (const float*)d_in[0];
    const int*   ei    = (const int*)d_in[1];
    const int*   batch = (const int*)d_in[2];
    const float* W[3]  = {(const float*)d_in[3], (const float*)d_in[7], (const float*)d_in[11]};
    const float* bbv[3] = {(const float*)d_in[4], (const float*)d_in[8], (const float*)d_in[12]};
    const float* gm[3] = {(const float*)d_in[5], (const float*)d_in[9], (const float*)d_in[13]};
    const float* bt[3] = {(const float*)d_in[6], (const float*)d_in[10], (const float*)d_in[14]};
    const float* Wc1 = (const float*)d_in[15];
    const float* bc1 = (const float*)d_in[16];
    const float* gc  = (const float*)d_in[17];
    const float* bec = (const float*)d_in[18];
    const float* Wc2 = (const float*)d_in[19];
    const float* bc2 = (const float*)d_in[20];
    float* out = (float*)d_out;

    // workspace carve-up (~210 MB)
    char* p = (char*)d_ws;
    float* hw  = (float*)p;  p += (size_t)MP * 512 * 4;   // GEMM out (padded rows)
    unsigned int* agg = (unsigned int*)p; p += (size_t)NN * 512 * 4;  // agg f32 / h packed
    unsigned short* Wh[3];
    unsigned short* Wl[3];
    Wh[0] = (unsigned short*)p; p += (size_t)512 * 768 * 2;
    Wl[0] = (unsigned short*)p; p += (size_t)512 * 768 * 2;
    Wh[1] = (unsigned short*)p; p += (size_t)256 * 512 * 2;
    Wl[1] = (unsigned short*)p; p += (size_t)256 * 512 * 2;
    Wh[2] = (unsigned short*)p; p += (size_t)128 * 256 * 2;
    Wl[2] = (unsigned short*)p; p += (size_t)128 * 256 * 2;
    float* dis   = (float*)p; p += (size_t)NN * 4;
    float* stats = (float*)p; p += 1024 * 4;
    float* pool  = (float*)p; p += (size_t)BB * 256 * 4;
    int* deg_i   = (int*)p; p += (size_t)NN * 4;
    int* rowptr  = (int*)p; p += (size_t)(NN + 1) * 4;
    int* cursor  = (int*)p; p += (size_t)NN * 4;
    int* bsum    = (int*)p; p += 256 * 4;
    int* boff    = (int*)p; p += 256 * 4;
    int* csr_src = (int*)p; p += (size_t)EE * 4;
    int* start   = (int*)p; p += (BB + 1) * 4;

    const int nb = (NN + 255) / 256;

    // weight plane split (tiny)
    cvt_wt_planes<<<(768 * 512 + 255) / 256, 256, 0, stream>>>(W[0], Wh[0], Wl[0], 768, 512);
    cvt_wt_planes<<<(512 * 256 + 255) / 256, 256, 0, stream>>>(W[1], Wh[1], Wl[1], 512, 256);
    cvt_wt_planes<<<(256 * 128 + 255) / 256, 256, 0, stream>>>(W[2], Wh[2], Wl[2], 256, 128);

    // degree + dis + CSR
    fill_i32<<<nb, 256, 0, stream>>>(deg_i, NN, 0);
    deg_edges<<<(EE + 255) / 256, 256, 0, stream>>>(ei, deg_i);
    rsqrt_k<<<nb, 256, 0, stream>>>(deg_i, dis);
    scan_block<<<nb, 256, 0, stream>>>(deg_i, rowptr, bsum);
    scan_sums<<<1, 256, 0, stream>>>(bsum, boff, nb);
    scan_fixup<<<nb, 256, 0, stream>>>(rowptr, boff);
    copy_i32<<<nb, 256, 0, stream>>>(rowptr, cursor, NN);
    fill_csr<<<(EE + 255) / 256, 256, 0, stream>>>(ei, cursor, csr_src);

    const int dims[4] = {768, 512, 256, 128};
    const int nstripe = (NN + 63) / 64;     // 782 blocks

    for (int l = 0; l < 3; ++l) {
        int K = dims[l], D = dims[l + 1];

        dim3 gg(D / 128, MP / 128);
        if (l == 0)
            gemm_split3<0><<<gg, 256, 0, stream>>>((const unsigned int*)x, Wh[0], Wl[0], hw, K, D);
        else
            gemm_split3<1><<<gg, 256, 0, stream>>>(agg, Wh[l], Wl[l], hw, K, D);

        fill_f32<<<(2 * D + 255) / 256, 256, 0, stream>>>(stats, 2 * D, 0.0f);
        agg_gather_st<<<nstripe, 256, 0, stream>>>(hw, (float*)agg, rowptr, csr_src,
                                                   dis, bbv[l], stats, D);

        size_t tot = (size_t)NN * D;
        bn_apply<<<(int)((tot + 255) / 256), 256, 0, stream>>>(agg, stats, gm[l], bt[l],
                                                               D, l < 2 ? 1 : 0, l < 2 ? 1 : 0);
    }

    find_starts<<<nb, 256, 0, stream>>>(batch, start);
    pool_kernel<<<BB, 128, 0, stream>>>((const float*)agg, start, pool);
    classifier_kernel<<<1, 256, 0, stream>>>(pool, Wc1, bc1, gc, bec, Wc2, bc2, out);
}

// Round 7
// 1159.389 us; speedup vs baseline: 1.1008x; 1.1008x over previous
//
#include <hip/hip_runtime.h>
#include <cstddef>

#define NN 50000
#define EE 400000
#define BB 64
#define MP 50048            // padded rows: 391 * 128
#define BN_EPS 1e-5f

typedef __attribute__((ext_vector_type(8))) short s16x8;
typedef __attribute__((ext_vector_type(4))) float f32x4;

#define GLOAD_LDS16(g, l) __builtin_amdgcn_global_load_lds( \
    (const __attribute__((address_space(1))) void*)(g),     \
    (__attribute__((address_space(3))) void*)(l), 16, 0, 0)

// ---------------- utility ----------------
__global__ void fill_f32(float* __restrict__ p, int n, float v) {
    int i = blockIdx.x * blockDim.x + threadIdx.x;
    if (i < n) p[i] = v;
}

__global__ void fill_i32(int* __restrict__ p, int n, int v) {
    int i = blockIdx.x * blockDim.x + threadIdx.x;
    if (i < n) p[i] = v;
}

__global__ void deg_edges(const int* __restrict__ ei, int* __restrict__ deg) {
    int e = blockIdx.x * blockDim.x + threadIdx.x;
    if (e < EE) atomicAdd(&deg[ei[EE + e]], 1);
}

__global__ void rsqrt_k(const int* __restrict__ deg, float* __restrict__ dis) {
    int i = blockIdx.x * blockDim.x + threadIdx.x;
    if (i < NN) dis[i] = rsqrtf((float)deg[i] + 1.0f);
}

// W [K][N] fp32 -> two bf16 planes Wh/Wl [N][K] (hi = truncate, lo = residual)
__global__ void cvt_wt_planes(const float* __restrict__ W,
                              unsigned short* __restrict__ Wh,
                              unsigned short* __restrict__ Wl,
                              int K, int N) {
    int i = blockIdx.x * blockDim.x + threadIdx.x;
    if (i >= K * N) return;
    int k = i / N, n = i % N;
    float f = W[i];
    unsigned int fb = __float_as_uint(f);
    unsigned int hif = fb & 0xFFFF0000u;
    float lo = f - __uint_as_float(hif);
    Wh[(size_t)n * K + k] = (unsigned short)(hif >> 16);
    Wl[(size_t)n * K + k] = (unsigned short)(__float_as_uint(lo) >> 16);
}

// ---------------- CSR build ----------------
__global__ __launch_bounds__(256) void scan_block(const int* __restrict__ deg,
                                                  int* __restrict__ rowptr,
                                                  int* __restrict__ bsum) {
    __shared__ int tmp[256];
    int tid = threadIdx.x;
    int i = blockIdx.x * 256 + tid;
    int v = (i < NN) ? deg[i] : 0;
    tmp[tid] = v;
    __syncthreads();
#pragma unroll
    for (int off = 1; off < 256; off <<= 1) {
        int t = (tid >= off) ? tmp[tid - off] : 0;
        __syncthreads();
        tmp[tid] += t;
        __syncthreads();
    }
    if (i < NN) rowptr[i] = tmp[tid] - v;
    if (tid == 255) bsum[blockIdx.x] = tmp[255];
}

__global__ __launch_bounds__(256) void scan_sums(const int* __restrict__ bsum,
                                                 int* __restrict__ boff, int nb) {
    __shared__ int tmp[256];
    int tid = threadIdx.x;
    int v = (tid < nb) ? bsum[tid] : 0;
    tmp[tid] = v;
    __syncthreads();
#pragma unroll
    for (int off = 1; off < 256; off <<= 1) {
        int t = (tid >= off) ? tmp[tid - off] : 0;
        __syncthreads();
        tmp[tid] += t;
        __syncthreads();
    }
    boff[tid] = tmp[tid] - v;
}

__global__ void scan_fixup(int* __restrict__ rowptr, const int* __restrict__ boff) {
    int i = blockIdx.x * blockDim.x + threadIdx.x;
    if (i < NN) rowptr[i] += boff[i >> 8];
    if (i == 0) rowptr[NN] = EE;
}

__global__ void copy_i32(const int* __restrict__ a, int* __restrict__ b, int n) {
    int i = blockIdx.x * blockDim.x + threadIdx.x;
    if (i < n) b[i] = a[i];
}

__global__ void fill_csr(const int* __restrict__ ei, int* __restrict__ cursor,
                         int* __restrict__ csr_src) {
    int e = blockIdx.x * blockDim.x + threadIdx.x;
    if (e >= EE) return;
    int s = ei[e];
    int t = ei[EE + e];
    int pos = atomicAdd(&cursor[t], 1);
    csr_src[pos] = s;
}

// ---------------- split helpers (mask/shift only — hardware-validated r5/r6) ------
// packed u32 p = (hi bf16 bits << 16) | (lo bf16 bits)
static __device__ __forceinline__ void unpack_pk(const uint4& u0, const uint4& u1,
                                                 s16x8& h, s16x8& l) {
    unsigned int p[8] = {u0.x, u0.y, u0.z, u0.w, u1.x, u1.y, u1.z, u1.w};
    union { s16x8 v; unsigned int u[4]; } H, L;
#pragma unroll
    for (int k = 0; k < 4; ++k) {
        H.u[k] = (p[2 * k + 1] & 0xFFFF0000u) | (p[2 * k] >> 16);
        L.u[k] = (p[2 * k + 1] << 16) | (p[2 * k] & 0xFFFFu);
    }
    h = H.v; l = L.v;
}

// 8 consecutive fp32 -> hi bf16 (truncate) + lo bf16 (residual)
static __device__ __forceinline__ void unpack_f32(const uint4& u0, const uint4& u1,
                                                  s16x8& h, s16x8& l) {
    unsigned int e[8] = {u0.x, u0.y, u0.z, u0.w, u1.x, u1.y, u1.z, u1.w};
    unsigned int hi[8], lo[8];
#pragma unroll
    for (int j = 0; j < 8; ++j) {
        hi[j] = e[j] & 0xFFFF0000u;
        float lf = __uint_as_float(e[j]) - __uint_as_float(hi[j]);
        lo[j] = __float_as_uint(lf);
    }
    union { s16x8 v; unsigned int u[4]; } H, L;
#pragma unroll
    for (int k = 0; k < 4; ++k) {
        H.u[k] = (hi[2 * k + 1]) | (hi[2 * k] >> 16);
        L.u[k] = (lo[2 * k + 1] & 0xFFFF0000u) | (lo[2 * k] >> 16);
    }
    h = H.v; l = L.v;
}

// ------ split-bf16 3-MFMA GEMM: C[MP,N] = dis[row] * (A[MP,K] @ W[N,K]^T) ------
// B pre-split into bf16 planes (zero B-unpack). AMODE 0: A fp32. AMODE 1: A packed.
// Epilogue folds the per-source-node dis scaling into the C-store (free).
template <int AMODE>
__global__ __launch_bounds__(256) void gemm_split3(const unsigned int* __restrict__ A,
                                                   const unsigned short* __restrict__ Bh,
                                                   const unsigned short* __restrict__ Bl,
                                                   float* __restrict__ C,
                                                   const float* __restrict__ dis,
                                                   int K, int N) {
    __shared__ unsigned int As[128 * 32];     // 16 KB  [row][k-u32]
    __shared__ unsigned short Bsh[128 * 32];  // 8 KB   [col][k]
    __shared__ unsigned short Bsl[128 * 32];  // 8 KB
    const int tid = threadIdx.x;
    const int w  = tid >> 6;
    const int lw = tid & 63;
    const int lo = lw & 15;
    const int hi = lw >> 4;
    const int wr = w >> 1, wc = w & 1;
    const int rowBase = blockIdx.y * 128;
    const int colBase = blockIdx.x * 128;

    const int arow = w * 8 + (lw >> 3);       // A staging: 8 rows/instr
    const int acol = (lw & 7) * 4;            // u32 col
    const int brow = w * 16 + (lw >> 2);      // B staging: 16 rows/instr
    const int bcol = (lw & 3) * 8;            // bf16 col

    f32x4 acc[4][4];
#pragma unroll
    for (int m = 0; m < 4; ++m)
#pragma unroll
        for (int n = 0; n < 4; ++n) acc[m][n] = (f32x4){0.f, 0.f, 0.f, 0.f};

    for (int k0 = 0; k0 < K; k0 += 32) {
#pragma unroll
        for (int i = 0; i < 4; ++i) {
            int gr = rowBase + i * 32 + arow;
            gr = (gr < NN) ? gr : (NN - 1);
            GLOAD_LDS16(A + (size_t)gr * K + k0 + acol, (char*)As + i * 4096 + w * 1024);
        }
#pragma unroll
        for (int j = 0; j < 2; ++j) {
            int gc = colBase + j * 64 + brow;
            GLOAD_LDS16(Bh + (size_t)gc * K + k0 + bcol, (char*)Bsh + j * 4096 + w * 1024);
            GLOAD_LDS16(Bl + (size_t)gc * K + k0 + bcol, (char*)Bsl + j * 4096 + w * 1024);
        }
        __syncthreads();

        s16x8 ah[4], al[4], bh[4], bl[4];
#pragma unroll
        for (int m = 0; m < 4; ++m) {
            int r = wr * 64 + m * 16 + lo;
            uint4 u0 = *(const uint4*)&As[r * 32 + hi * 8];
            uint4 u1 = *(const uint4*)&As[r * 32 + hi * 8 + 4];
            if (AMODE == 0) unpack_f32(u0, u1, ah[m], al[m]);
            else            unpack_pk(u0, u1, ah[m], al[m]);
        }
#pragma unroll
        for (int n = 0; n < 4; ++n) {
            int r = wc * 64 + n * 16 + lo;
            bh[n] = *(const s16x8*)&Bsh[r * 32 + hi * 8];
            bl[n] = *(const s16x8*)&Bsl[r * 32 + hi * 8];
        }
#pragma unroll
        for (int m = 0; m < 4; ++m)
#pragma unroll
            for (int n = 0; n < 4; ++n) {
                acc[m][n] = __builtin_amdgcn_mfma_f32_16x16x32_bf16(ah[m], bh[n], acc[m][n], 0, 0, 0);
                acc[m][n] = __builtin_amdgcn_mfma_f32_16x16x32_bf16(ah[m], bl[n], acc[m][n], 0, 0, 0);
                acc[m][n] = __builtin_amdgcn_mfma_f32_16x16x32_bf16(al[m], bh[n], acc[m][n], 0, 0, 0);
            }
        __syncthreads();
    }

#pragma unroll
    for (int m = 0; m < 4; ++m) {
        int row0 = rowBase + wr * 64 + m * 16 + hi * 4;
#pragma unroll
        for (int j = 0; j < 4; ++j) {
            int r = row0 + j;
            float ds = dis[(r < NN) ? r : (NN - 1)];
#pragma unroll
            for (int n = 0; n < 4; ++n) {
                int col = colBase + wc * 64 + n * 16 + lo;
                C[(size_t)r * N + col] = ds * acc[m][n][j];
            }
        }
    }
}

// ------ gather aggregation (per-node parallel, dis pre-folded, 4-edge unroll) ------
// hws[r] = dis[r]*hw[r];  agg[n] = dis[n]*(hws[n] + sum_e hws[src_e]) + bias
__global__ __launch_bounds__(256) void agg_gather(const float* __restrict__ hws,
                                                  float* __restrict__ agg,
                                                  const int* __restrict__ rowptr,
                                                  const int* __restrict__ csr_src,
                                                  const float* __restrict__ dis,
                                                  const float* __restrict__ bias,
                                                  int D) {
    const int tpn = D >> 2;
    const int npb = 256 / tpn;
    const int local = threadIdx.x / tpn;
    const int lane = threadIdx.x % tpn;
    const int n = blockIdx.x * npb + local;
    if (n >= NN) return;
    const int dq = lane * 4;

    float4 acc = *reinterpret_cast<const float4*>(&hws[(size_t)n * D + dq]);  // self
    int e0 = rowptr[n], e1 = rowptr[n + 1];
    int e = e0;
    for (; e + 4 <= e1; e += 4) {
        int s0 = csr_src[e + 0];
        int s1 = csr_src[e + 1];
        int s2 = csr_src[e + 2];
        int s3 = csr_src[e + 3];
        float4 v0 = *reinterpret_cast<const float4*>(&hws[(size_t)s0 * D + dq]);
        float4 v1 = *reinterpret_cast<const float4*>(&hws[(size_t)s1 * D + dq]);
        float4 v2 = *reinterpret_cast<const float4*>(&hws[(size_t)s2 * D + dq]);
        float4 v3 = *reinterpret_cast<const float4*>(&hws[(size_t)s3 * D + dq]);
        acc.x += (v0.x + v1.x) + (v2.x + v3.x);
        acc.y += (v0.y + v1.y) + (v2.y + v3.y);
        acc.z += (v0.z + v1.z) + (v2.z + v3.z);
        acc.w += (v0.w + v1.w) + (v2.w + v3.w);
    }
    for (; e < e1; ++e) {
        int s = csr_src[e];
        float4 v = *reinterpret_cast<const float4*>(&hws[(size_t)s * D + dq]);
        acc.x += v.x; acc.y += v.y; acc.z += v.z; acc.w += v.w;
    }
    float din = dis[n];
    float4 bsv = *reinterpret_cast<const float4*>(&bias[dq]);
    float4 o;
    o.x = din * acc.x + bsv.x;
    o.y = din * acc.y + bsv.y;
    o.z = din * acc.z + bsv.z;
    o.w = din * acc.w + bsv.w;
    *reinterpret_cast<float4*>(&agg[(size_t)n * D + dq]) = o;
}

// ---------------- batchnorm stats (column-striped, r5-validated) ----------------
__global__ void bn_stats(const float* __restrict__ h, float* __restrict__ stats, int D) {
    int d = blockIdx.x * blockDim.x + threadIdx.x;
    if (d >= D) return;
    float s = 0.f, ss = 0.f;
    for (int n = blockIdx.y; n < NN; n += gridDim.y) {
        float v = h[(size_t)n * D + d];
        s += v;
        ss += v * v;
    }
    atomicAdd(&stats[d], s);
    atomicAdd(&stats[D + d], ss);
}

// ---------------- batchnorm apply (fp32 in-place; optional split-pack out) -------
__global__ void bn_apply(unsigned int* __restrict__ buf,
                         const float* __restrict__ stats,
                         const float* __restrict__ gamma, const float* __restrict__ beta,
                         int D, int do_relu, int do_pack) {
    size_t i = (size_t)blockIdx.x * blockDim.x + threadIdx.x;
    if (i >= (size_t)NN * D) return;
    int d = (int)(i % (size_t)D);
    float mean = stats[d] * (1.0f / NN);
    float var  = stats[D + d] * (1.0f / NN) - mean * mean;
    float f = (__uint_as_float(buf[i]) - mean) * rsqrtf(var + BN_EPS) * gamma[d] + beta[d];
    if (do_relu) f = fmaxf(f, 0.f);
    if (do_pack) {
        unsigned int fb = __float_as_uint(f);
        unsigned int hif = fb & 0xFFFF0000u;
        float lf = f - __uint_as_float(hif);
        buf[i] = hif | (__float_as_uint(lf) >> 16);
    } else {
        buf[i] = __float_as_uint(f);
    }
}

// ---------------- pooling ----------------
__global__ void find_starts(const int* __restrict__ batch, int* __restrict__ start) {
    int n = blockIdx.x * blockDim.x + threadIdx.x;
    if (n >= NN) return;
    int bc = batch[n];
    int bp = (n == 0) ? -1 : batch[n - 1];
    for (int g = bp + 1; g <= bc; ++g) start[g] = n;
    if (n == NN - 1) {
        for (int g = bc + 1; g <= BB; ++g) start[g] = NN;
    }
}

__global__ void pool_kernel(const float* __restrict__ h, const int* __restrict__ start,
                            float* __restrict__ pool) {
    int b = blockIdx.x;
    int d = threadIdx.x;
    int s0 = start[b], s1 = start[b + 1];
    float sum = 0.f;
    float mx = -3.402823466e+38f;
    for (int n = s0; n < s1; ++n) {
        float v = h[(size_t)n * 128 + d];
        sum += v;
        mx = fmaxf(mx, v);
    }
    float cnt = fmaxf((float)(s1 - s0), 1.0f);
    pool[b * 256 + d] = sum / cnt;
    pool[b * 256 + 128 + d] = mx;
}

// ---------------- classifier (single block, fp32) ----------------
__global__ __launch_bounds__(256) void classifier_kernel(
        const float* __restrict__ pool,
        const float* __restrict__ Wc1, const float* __restrict__ bc1,
        const float* __restrict__ gc, const float* __restrict__ bec,
        const float* __restrict__ Wc2, const float* __restrict__ bc2,
        float* __restrict__ out) {
    __shared__ float hc[64][65];
    __shared__ float cmean[64];
    __shared__ float crstd[64];
    int tid = threadIdx.x;

    for (int i = tid; i < 64 * 64; i += 256) {
        int r = i / 64, c = i % 64;
        float acc = bc1[c];
        for (int k = 0; k < 256; ++k)
            acc += pool[r * 256 + k] * Wc1[k * 64 + c];
        hc[r][c] = fmaxf(acc, 0.f);
    }
    __syncthreads();

    if (tid < 64) {
        float s = 0.f, ss = 0.f;
        for (int r = 0; r < 64; ++r) {
            float v = hc[r][tid];
            s += v;
            ss += v * v;
        }
        float m = s * (1.0f / 64.0f);
        float var = ss * (1.0f / 64.0f) - m * m;
        cmean[tid] = m;
        crstd[tid] = rsqrtf(var + BN_EPS);
    }
    __syncthreads();

    if (tid < 128) {
        int r = tid / 2, k = tid % 2;
        float acc = bc2[k];
        for (int c = 0; c < 64; ++c) {
            float v = (hc[r][c] - cmean[c]) * crstd[c] * gc[c] + bec[c];
            acc += v * Wc2[c * 2 + k];
        }
        out[r * 2 + k] = acc;
    }
}

// ---------------- launch ----------------
extern "C" void kernel_launch(void* const* d_in, const int* in_sizes, int n_in,
                              void* d_out, int out_size, void* d_ws, size_t ws_size,
                              hipStream_t stream) {
    const float* x     = (const float*)d_in[0];
    const int*   ei    = (const int*)d_in[1];
    const int*   batch = (const int*)d_in[2];
    const float* W[3]  = {(const float*)d_in[3], (const float*)d_in[7], (const float*)d_in[11]};
    const float* bbv[3] = {(const float*)d_in[4], (const float*)d_in[8], (const float*)d_in[12]};
    const float* gm[3] = {(const float*)d_in[5], (const float*)d_in[9], (const float*)d_in[13]};
    const float* bt[3] = {(const float*)d_in[6], (const float*)d_in[10], (const float*)d_in[14]};
    const float* Wc1 = (const float*)d_in[15];
    const float* bc1 = (const float*)d_in[16];
    const float* gc  = (const float*)d_in[17];
    const float* bec = (const float*)d_in[18];
    const float* Wc2 = (const float*)d_in[19];
    const float* bc2 = (const float*)d_in[20];
    float* out = (float*)d_out;

    // workspace carve-up (~211 MB)
    char* p = (char*)d_ws;
    float* hw  = (float*)p;  p += (size_t)MP * 512 * 4;   // dis-scaled GEMM out
    unsigned int* agg = (unsigned int*)p; p += (size_t)NN * 512 * 4;  // agg f32 / h packed
    unsigned short* Wh[3];
    unsigned short* Wl[3];
    Wh[0] = (unsigned short*)p; p += (size_t)512 * 768 * 2;
    Wl[0] = (unsigned short*)p; p += (size_t)512 * 768 * 2;
    Wh[1] = (unsigned short*)p; p += (size_t)256 * 512 * 2;
    Wl[1] = (unsigned short*)p; p += (size_t)256 * 512 * 2;
    Wh[2] = (unsigned short*)p; p += (size_t)128 * 256 * 2;
    Wl[2] = (unsigned short*)p; p += (size_t)128 * 256 * 2;
    float* dis   = (float*)p; p += (size_t)NN * 4;
    float* stats = (float*)p; p += 1024 * 4;
    float* pool  = (float*)p; p += (size_t)BB * 256 * 4;
    int* deg_i   = (int*)p; p += (size_t)NN * 4;
    int* rowptr  = (int*)p; p += (size_t)(NN + 1) * 4;
    int* cursor  = (int*)p; p += (size_t)NN * 4;
    int* bsum    = (int*)p; p += 256 * 4;
    int* boff    = (int*)p; p += 256 * 4;
    int* csr_src = (int*)p; p += (size_t)EE * 4;
    int* start   = (int*)p; p += (BB + 1) * 4;

    const int nb = (NN + 255) / 256;

    // weight plane split (tiny)
    cvt_wt_planes<<<(768 * 512 + 255) / 256, 256, 0, stream>>>(W[0], Wh[0], Wl[0], 768, 512);
    cvt_wt_planes<<<(512 * 256 + 255) / 256, 256, 0, stream>>>(W[1], Wh[1], Wl[1], 512, 256);
    cvt_wt_planes<<<(256 * 128 + 255) / 256, 256, 0, stream>>>(W[2], Wh[2], Wl[2], 256, 128);

    // degree + dis + CSR
    fill_i32<<<nb, 256, 0, stream>>>(deg_i, NN, 0);
    deg_edges<<<(EE + 255) / 256, 256, 0, stream>>>(ei, deg_i);
    rsqrt_k<<<nb, 256, 0, stream>>>(deg_i, dis);
    scan_block<<<nb, 256, 0, stream>>>(deg_i, rowptr, bsum);
    scan_sums<<<1, 256, 0, stream>>>(bsum, boff, nb);
    scan_fixup<<<nb, 256, 0, stream>>>(rowptr, boff);
    copy_i32<<<nb, 256, 0, stream>>>(rowptr, cursor, NN);
    fill_csr<<<(EE + 255) / 256, 256, 0, stream>>>(ei, cursor, csr_src);

    const int dims[4] = {768, 512, 256, 128};

    for (int l = 0; l < 3; ++l) {
        int K = dims[l], D = dims[l + 1];

        dim3 gg(D / 128, MP / 128);
        if (l == 0)
            gemm_split3<0><<<gg, 256, 0, stream>>>((const unsigned int*)x, Wh[0], Wl[0],
                                                   hw, dis, K, D);
        else
            gemm_split3<1><<<gg, 256, 0, stream>>>(agg, Wh[l], Wl[l], hw, dis, K, D);

        int tpn = D / 4;
        int npb = 256 / tpn;
        agg_gather<<<(NN + npb - 1) / npb, 256, 0, stream>>>(hw, (float*)agg, rowptr, csr_src,
                                                             dis, bbv[l], D);

        fill_f32<<<(2 * D + 255) / 256, 256, 0, stream>>>(stats, 2 * D, 0.0f);
        bn_stats<<<dim3((D + 255) / 256, 256), 256, 0, stream>>>((const float*)agg, stats, D);
        size_t tot = (size_t)NN * D;
        bn_apply<<<(int)((tot + 255) / 256), 256, 0, stream>>>(agg, stats, gm[l], bt[l],
                                                               D, l < 2 ? 1 : 0, l < 2 ? 1 : 0);
    }

    find_starts<<<nb, 256, 0, stream>>>(batch, start);
    pool_kernel<<<BB, 128, 0, stream>>>((const float*)agg, start, pool);
    classifier_kernel<<<1, 256, 0, stream>>>(pool, Wc1, bc1, gc, bec, Wc2, bc2, out);
}

// Round 8
// 1012.373 us; speedup vs baseline: 1.2606x; 1.1452x over previous
//
#include <hip/hip_runtime.h>
#include <cstddef>

#define NN 50000
#define EE 400000
#define BB 64
#define MP 50048            // padded rows: 391 * 128
#define BN_EPS 1e-5f

typedef __attribute__((ext_vector_type(8))) short s16x8;
typedef __attribute__((ext_vector_type(4))) float f32x4;
typedef __attribute__((ext_vector_type(8))) _Float16 f16x8;

#define GLOAD_LDS16(g, l) __builtin_amdgcn_global_load_lds( \
    (const __attribute__((address_space(1))) void*)(g),     \
    (__attribute__((address_space(3))) void*)(l), 16, 0, 0)

// ---------------- utility ----------------
__global__ void fill_f32(float* __restrict__ p, int n, float v) {
    int i = blockIdx.x * blockDim.x + threadIdx.x;
    if (i < n) p[i] = v;
}

__global__ void fill_i32(int* __restrict__ p, int n, int v) {
    int i = blockIdx.x * blockDim.x + threadIdx.x;
    if (i < n) p[i] = v;
}

__global__ void deg_edges(const int* __restrict__ ei, int* __restrict__ deg) {
    int e = blockIdx.x * blockDim.x + threadIdx.x;
    if (e < EE) atomicAdd(&deg[ei[EE + e]], 1);
}

// W [K][N] fp32 -> two bf16 planes Wh/Wl [N][K] (hi = truncate, lo = residual)
__global__ void cvt_wt_planes(const float* __restrict__ W,
                              unsigned short* __restrict__ Wh,
                              unsigned short* __restrict__ Wl,
                              int K, int N) {
    int i = blockIdx.x * blockDim.x + threadIdx.x;
    if (i >= K * N) return;
    int k = i / N, n = i % N;
    float f = W[i];
    unsigned int fb = __float_as_uint(f);
    unsigned int hif = fb & 0xFFFF0000u;
    float lo = f - __uint_as_float(hif);
    Wh[(size_t)n * K + k] = (unsigned short)(hif >> 16);
    Wl[(size_t)n * K + k] = (unsigned short)(__float_as_uint(lo) >> 16);
}

// ---------------- CSR build (scan; rsqrt fused here) ----------------
__global__ __launch_bounds__(256) void scan_block(const int* __restrict__ deg,
                                                  int* __restrict__ rowptr,
                                                  int* __restrict__ bsum,
                                                  float* __restrict__ dis) {
    __shared__ int tmp[256];
    int tid = threadIdx.x;
    int i = blockIdx.x * 256 + tid;
    int v = (i < NN) ? deg[i] : 0;
    if (i < NN) dis[i] = rsqrtf((float)v + 1.0f);
    tmp[tid] = v;
    __syncthreads();
#pragma unroll
    for (int off = 1; off < 256; off <<= 1) {
        int t = (tid >= off) ? tmp[tid - off] : 0;
        __syncthreads();
        tmp[tid] += t;
        __syncthreads();
    }
    if (i < NN) rowptr[i] = tmp[tid] - v;
    if (tid == 255) bsum[blockIdx.x] = tmp[255];
}

__global__ __launch_bounds__(256) void scan_sums(const int* __restrict__ bsum,
                                                 int* __restrict__ boff, int nb) {
    __shared__ int tmp[256];
    int tid = threadIdx.x;
    int v = (tid < nb) ? bsum[tid] : 0;
    tmp[tid] = v;
    __syncthreads();
#pragma unroll
    for (int off = 1; off < 256; off <<= 1) {
        int t = (tid >= off) ? tmp[tid - off] : 0;
        __syncthreads();
        tmp[tid] += t;
        __syncthreads();
    }
    boff[tid] = tmp[tid] - v;
}

// fixup also seeds cursor (copy of rowptr)
__global__ void scan_fixup(int* __restrict__ rowptr, const int* __restrict__ boff,
                           int* __restrict__ cursor) {
    int i = blockIdx.x * blockDim.x + threadIdx.x;
    if (i < NN) {
        int v = rowptr[i] + boff[i >> 8];
        rowptr[i] = v;
        cursor[i] = v;
    }
    if (i == 0) rowptr[NN] = EE;
}

__global__ void fill_csr(const int* __restrict__ ei, int* __restrict__ cursor,
                         int* __restrict__ csr_src) {
    int e = blockIdx.x * blockDim.x + threadIdx.x;
    if (e >= EE) return;
    int s = ei[e];
    int t = ei[EE + e];
    int pos = atomicAdd(&cursor[t], 1);
    csr_src[pos] = s;
}

// ---------------- split helpers (mask/shift only — hardware-validated r5-r7) ------
static __device__ __forceinline__ void unpack_pk(const uint4& u0, const uint4& u1,
                                                 s16x8& h, s16x8& l) {
    unsigned int p[8] = {u0.x, u0.y, u0.z, u0.w, u1.x, u1.y, u1.z, u1.w};
    union { s16x8 v; unsigned int u[4]; } H, L;
#pragma unroll
    for (int k = 0; k < 4; ++k) {
        H.u[k] = (p[2 * k + 1] & 0xFFFF0000u) | (p[2 * k] >> 16);
        L.u[k] = (p[2 * k + 1] << 16) | (p[2 * k] & 0xFFFFu);
    }
    h = H.v; l = L.v;
}

static __device__ __forceinline__ void unpack_f32(const uint4& u0, const uint4& u1,
                                                  s16x8& h, s16x8& l) {
    unsigned int e[8] = {u0.x, u0.y, u0.z, u0.w, u1.x, u1.y, u1.z, u1.w};
    unsigned int hi[8], lo[8];
#pragma unroll
    for (int j = 0; j < 8; ++j) {
        hi[j] = e[j] & 0xFFFF0000u;
        float lf = __uint_as_float(e[j]) - __uint_as_float(hi[j]);
        lo[j] = __float_as_uint(lf);
    }
    union { s16x8 v; unsigned int u[4]; } H, L;
#pragma unroll
    for (int k = 0; k < 4; ++k) {
        H.u[k] = (hi[2 * k + 1]) | (hi[2 * k] >> 16);
        L.u[k] = (lo[2 * k + 1] & 0xFFFF0000u) | (lo[2 * k] >> 16);
    }
    h = H.v; l = L.v;
}

// ------ split-bf16 3-MFMA GEMM: C[MP,N] = dis[row] * (A[MP,K] @ W[N,K]^T), fp16 out --
template <int AMODE>
__global__ __launch_bounds__(256) void gemm_split3(const unsigned int* __restrict__ A,
                                                   const unsigned short* __restrict__ Bh,
                                                   const unsigned short* __restrict__ Bl,
                                                   _Float16* __restrict__ C,
                                                   const float* __restrict__ dis,
                                                   int K, int N) {
    __shared__ unsigned int As[128 * 32];     // 16 KB  [row][k-u32]
    __shared__ unsigned short Bsh[128 * 32];  // 8 KB   [col][k]
    __shared__ unsigned short Bsl[128 * 32];  // 8 KB
    const int tid = threadIdx.x;
    const int w  = tid >> 6;
    const int lw = tid & 63;
    const int lo = lw & 15;
    const int hi = lw >> 4;
    const int wr = w >> 1, wc = w & 1;
    const int rowBase = blockIdx.y * 128;
    const int colBase = blockIdx.x * 128;

    const int arow = w * 8 + (lw >> 3);
    const int acol = (lw & 7) * 4;
    const int brow = w * 16 + (lw >> 2);
    const int bcol = (lw & 3) * 8;

    f32x4 acc[4][4];
#pragma unroll
    for (int m = 0; m < 4; ++m)
#pragma unroll
        for (int n = 0; n < 4; ++n) acc[m][n] = (f32x4){0.f, 0.f, 0.f, 0.f};

    for (int k0 = 0; k0 < K; k0 += 32) {
#pragma unroll
        for (int i = 0; i < 4; ++i) {
            int gr = rowBase + i * 32 + arow;
            gr = (gr < NN) ? gr : (NN - 1);
            GLOAD_LDS16(A + (size_t)gr * K + k0 + acol, (char*)As + i * 4096 + w * 1024);
        }
#pragma unroll
        for (int j = 0; j < 2; ++j) {
            int gc = colBase + j * 64 + brow;
            GLOAD_LDS16(Bh + (size_t)gc * K + k0 + bcol, (char*)Bsh + j * 4096 + w * 1024);
            GLOAD_LDS16(Bl + (size_t)gc * K + k0 + bcol, (char*)Bsl + j * 4096 + w * 1024);
        }
        __syncthreads();

        s16x8 ah[4], al[4], bh[4], bl[4];
#pragma unroll
        for (int m = 0; m < 4; ++m) {
            int r = wr * 64 + m * 16 + lo;
            uint4 u0 = *(const uint4*)&As[r * 32 + hi * 8];
            uint4 u1 = *(const uint4*)&As[r * 32 + hi * 8 + 4];
            if (AMODE == 0) unpack_f32(u0, u1, ah[m], al[m]);
            else            unpack_pk(u0, u1, ah[m], al[m]);
        }
#pragma unroll
        for (int n = 0; n < 4; ++n) {
            int r = wc * 64 + n * 16 + lo;
            bh[n] = *(const s16x8*)&Bsh[r * 32 + hi * 8];
            bl[n] = *(const s16x8*)&Bsl[r * 32 + hi * 8];
        }
#pragma unroll
        for (int m = 0; m < 4; ++m)
#pragma unroll
            for (int n = 0; n < 4; ++n) {
                acc[m][n] = __builtin_amdgcn_mfma_f32_16x16x32_bf16(ah[m], bh[n], acc[m][n], 0, 0, 0);
                acc[m][n] = __builtin_amdgcn_mfma_f32_16x16x32_bf16(ah[m], bl[n], acc[m][n], 0, 0, 0);
                acc[m][n] = __builtin_amdgcn_mfma_f32_16x16x32_bf16(al[m], bh[n], acc[m][n], 0, 0, 0);
            }
        __syncthreads();
    }

#pragma unroll
    for (int m = 0; m < 4; ++m) {
        int row0 = rowBase + wr * 64 + m * 16 + hi * 4;
#pragma unroll
        for (int j = 0; j < 4; ++j) {
            int r = row0 + j;
            float ds = dis[(r < NN) ? r : (NN - 1)];
#pragma unroll
            for (int n = 0; n < 4; ++n) {
                int col = colBase + wc * 64 + n * 16 + lo;
                C[(size_t)r * N + col] = (_Float16)(ds * acc[m][n][j]);
            }
        }
    }
}

// ------ gather aggregation: fp16 hws in, fp32 agg out, 4-edge unroll ------
// agg[n] = dis[n]*(hws[n] + sum_e hws[src_e]) + bias
__global__ __launch_bounds__(256) void agg_gather(const _Float16* __restrict__ hws,
                                                  float* __restrict__ agg,
                                                  const int* __restrict__ rowptr,
                                                  const int* __restrict__ csr_src,
                                                  const float* __restrict__ dis,
                                                  const float* __restrict__ bias,
                                                  int D) {
    const int tpn = D >> 3;                  // threads per node (8 ch each)
    const int npb = 256 / tpn;
    const int local = threadIdx.x / tpn;
    const int lane = threadIdx.x % tpn;
    const int n = blockIdx.x * npb + local;
    if (n >= NN) return;
    const int dq = lane * 8;

    f16x8 sv = *(const f16x8*)&hws[(size_t)n * D + dq];
    float a[8];
#pragma unroll
    for (int j = 0; j < 8; ++j) a[j] = (float)sv[j];

    int e0 = rowptr[n], e1 = rowptr[n + 1];
    int e = e0;
    for (; e + 4 <= e1; e += 4) {
        int s0 = csr_src[e + 0];
        int s1 = csr_src[e + 1];
        int s2 = csr_src[e + 2];
        int s3 = csr_src[e + 3];
        f16x8 v0 = *(const f16x8*)&hws[(size_t)s0 * D + dq];
        f16x8 v1 = *(const f16x8*)&hws[(size_t)s1 * D + dq];
        f16x8 v2 = *(const f16x8*)&hws[(size_t)s2 * D + dq];
        f16x8 v3 = *(const f16x8*)&hws[(size_t)s3 * D + dq];
#pragma unroll
        for (int j = 0; j < 8; ++j)
            a[j] += ((float)v0[j] + (float)v1[j]) + ((float)v2[j] + (float)v3[j]);
    }
    for (; e < e1; ++e) {
        int s = csr_src[e];
        f16x8 v = *(const f16x8*)&hws[(size_t)s * D + dq];
#pragma unroll
        for (int j = 0; j < 8; ++j) a[j] += (float)v[j];
    }

    float din = dis[n];
    f32x4 o0, o1;
#pragma unroll
    for (int j = 0; j < 4; ++j) o0[j] = din * a[j] + bias[dq + j];
#pragma unroll
    for (int j = 0; j < 4; ++j) o1[j] = din * a[4 + j] + bias[dq + 4 + j];
    *(f32x4*)&agg[(size_t)n * D + dq] = o0;
    *(f32x4*)&agg[(size_t)n * D + dq + 4] = o1;
}

// ---------------- batchnorm stats (column-striped, validated) ----------------
__global__ void bn_stats(const float* __restrict__ h, float* __restrict__ stats, int D) {
    int d = blockIdx.x * blockDim.x + threadIdx.x;
    if (d >= D) return;
    float s = 0.f, ss = 0.f;
    for (int n = blockIdx.y; n < NN; n += gridDim.y) {
        float v = h[(size_t)n * D + d];
        s += v;
        ss += v * v;
    }
    atomicAdd(&stats[d], s);
    atomicAdd(&stats[D + d], ss);
}

// ---------------- batchnorm apply (relu + split-pack; layers 0,1) ----------------
__global__ void bn_apply(unsigned int* __restrict__ buf,
                         const float* __restrict__ stats,
                         const float* __restrict__ gamma, const float* __restrict__ beta,
                         int D) {
    size_t i = (size_t)blockIdx.x * blockDim.x + threadIdx.x;
    if (i >= (size_t)NN * D) return;
    int d = (int)(i % (size_t)D);
    float mean = stats[d] * (1.0f / NN);
    float var  = stats[D + d] * (1.0f / NN) - mean * mean;
    float f = (__uint_as_float(buf[i]) - mean) * rsqrtf(var + BN_EPS) * gamma[d] + beta[d];
    f = fmaxf(f, 0.f);
    unsigned int fb = __float_as_uint(f);
    unsigned int hif = fb & 0xFFFF0000u;
    float lf = f - __uint_as_float(hif);
    buf[i] = hif | (__float_as_uint(lf) >> 16);
}

// ---------------- layer-2 BN coefficients: c1 = gamma*rstd, c2 = beta - mean*c1 ----
__global__ void bn_coef(const float* __restrict__ stats,
                        const float* __restrict__ gamma, const float* __restrict__ beta,
                        float* __restrict__ c1, float* __restrict__ c2, int D) {
    int d = blockIdx.x * blockDim.x + threadIdx.x;
    if (d >= D) return;
    float mean = stats[d] * (1.0f / NN);
    float var  = stats[D + d] * (1.0f / NN) - mean * mean;
    float r = rsqrtf(var + BN_EPS) * gamma[d];
    c1[d] = r;
    c2[d] = beta[d] - mean * r;
}

// ---------------- pooling with fused BN affine ----------------
__global__ void find_starts(const int* __restrict__ batch, int* __restrict__ start) {
    int n = blockIdx.x * blockDim.x + threadIdx.x;
    if (n >= NN) return;
    int bc = batch[n];
    int bp = (n == 0) ? -1 : batch[n - 1];
    for (int g = bp + 1; g <= bc; ++g) start[g] = n;
    if (n == NN - 1) {
        for (int g = bc + 1; g <= BB; ++g) start[g] = NN;
    }
}

__global__ void pool_bn(const float* __restrict__ h, const int* __restrict__ start,
                        const float* __restrict__ c1, const float* __restrict__ c2,
                        float* __restrict__ pool) {
    int b = blockIdx.x;
    int d = threadIdx.x;
    int s0 = start[b], s1 = start[b + 1];
    float a1 = c1[d], a2 = c2[d];
    float sum = 0.f;
    float mx = -3.402823466e+38f;
    for (int n = s0; n < s1; ++n) {
        float v = a1 * h[(size_t)n * 128 + d] + a2;
        sum += v;
        mx = fmaxf(mx, v);
    }
    float cnt = fmaxf((float)(s1 - s0), 1.0f);
    pool[b * 256 + d] = sum / cnt;
    pool[b * 256 + 128 + d] = mx;
}

// ---------------- classifier (single block, fp32) ----------------
__global__ __launch_bounds__(256) void classifier_kernel(
        const float* __restrict__ pool,
        const float* __restrict__ Wc1, const float* __restrict__ bc1,
        const float* __restrict__ gc, const float* __restrict__ bec,
        const float* __restrict__ Wc2, const float* __restrict__ bc2,
        float* __restrict__ out) {
    __shared__ float hc[64][65];
    __shared__ float cmean[64];
    __shared__ float crstd[64];
    int tid = threadIdx.x;

    for (int i = tid; i < 64 * 64; i += 256) {
        int r = i / 64, c = i % 64;
        float acc = bc1[c];
        for (int k = 0; k < 256; ++k)
            acc += pool[r * 256 + k] * Wc1[k * 64 + c];
        hc[r][c] = fmaxf(acc, 0.f);
    }
    __syncthreads();

    if (tid < 64) {
        float s = 0.f, ss = 0.f;
        for (int r = 0; r < 64; ++r) {
            float v = hc[r][tid];
            s += v;
            ss += v * v;
        }
        float m = s * (1.0f / 64.0f);
        float var = ss * (1.0f / 64.0f) - m * m;
        cmean[tid] = m;
        crstd[tid] = rsqrtf(var + BN_EPS);
    }
    __syncthreads();

    if (tid < 128) {
        int r = tid / 2, k = tid % 2;
        float acc = bc2[k];
        for (int c = 0; c < 64; ++c) {
            float v = (hc[r][c] - cmean[c]) * crstd[c] * gc[c] + bec[c];
            acc += v * Wc2[c * 2 + k];
        }
        out[r * 2 + k] = acc;
    }
}

// ---------------- launch ----------------
extern "C" void kernel_launch(void* const* d_in, const int* in_sizes, int n_in,
                              void* d_out, int out_size, void* d_ws, size_t ws_size,
                              hipStream_t stream) {
    const float* x     = (const float*)d_in[0];
    const int*   ei    = (const int*)d_in[1];
    const int*   batch = (const int*)d_in[2];
    const float* W[3]  = {(const float*)d_in[3], (const float*)d_in[7], (const float*)d_in[11]};
    const float* bbv[3] = {(const float*)d_in[4], (const float*)d_in[8], (const float*)d_in[12]};
    const float* gm[3] = {(const float*)d_in[5], (const float*)d_in[9], (const float*)d_in[13]};
    const float* bt[3] = {(const float*)d_in[6], (const float*)d_in[10], (const float*)d_in[14]};
    const float* Wc1 = (const float*)d_in[15];
    const float* bc1 = (const float*)d_in[16];
    const float* gc  = (const float*)d_in[17];
    const float* bec = (const float*)d_in[18];
    const float* Wc2 = (const float*)d_in[19];
    const float* bc2 = (const float*)d_in[20];
    float* out = (float*)d_out;

    // workspace carve-up
    char* p = (char*)d_ws;
    _Float16* hw = (_Float16*)p; p += (size_t)MP * 512 * 2;           // fp16 dis-scaled GEMM out
    unsigned int* agg = (unsigned int*)p; p += (size_t)NN * 512 * 4;  // agg f32 / h packed
    unsigned short* Wh[3];
    unsigned short* Wl[3];
    Wh[0] = (unsigned short*)p; p += (size_t)512 * 768 * 2;
    Wl[0] = (unsigned short*)p; p += (size_t)512 * 768 * 2;
    Wh[1] = (unsigned short*)p; p += (size_t)256 * 512 * 2;
    Wl[1] = (unsigned short*)p; p += (size_t)256 * 512 * 2;
    Wh[2] = (unsigned short*)p; p += (size_t)128 * 256 * 2;
    Wl[2] = (unsigned short*)p; p += (size_t)128 * 256 * 2;
    float* dis   = (float*)p; p += (size_t)NN * 4;
    float* stats = (float*)p; p += 1024 * 4;     // [0:2D) sums; c1 at +512, c2 at +640
    float* pool  = (float*)p; p += (size_t)BB * 256 * 4;
    int* deg_i   = (int*)p; p += (size_t)NN * 4;
    int* rowptr  = (int*)p; p += (size_t)(NN + 1) * 4;
    int* cursor  = (int*)p; p += (size_t)NN * 4;
    int* bsum    = (int*)p; p += 256 * 4;
    int* boff    = (int*)p; p += 256 * 4;
    int* csr_src = (int*)p; p += (size_t)EE * 4;
    int* start   = (int*)p; p += (BB + 1) * 4;
    float* c1 = stats + 512;
    float* c2 = stats + 640;

    const int nb = (NN + 255) / 256;

    // weight plane split (tiny)
    cvt_wt_planes<<<(768 * 512 + 255) / 256, 256, 0, stream>>>(W[0], Wh[0], Wl[0], 768, 512);
    cvt_wt_planes<<<(512 * 256 + 255) / 256, 256, 0, stream>>>(W[1], Wh[1], Wl[1], 512, 256);
    cvt_wt_planes<<<(256 * 128 + 255) / 256, 256, 0, stream>>>(W[2], Wh[2], Wl[2], 256, 128);

    // degree + dis + CSR
    fill_i32<<<nb, 256, 0, stream>>>(deg_i, NN, 0);
    deg_edges<<<(EE + 255) / 256, 256, 0, stream>>>(ei, deg_i);
    scan_block<<<nb, 256, 0, stream>>>(deg_i, rowptr, bsum, dis);
    scan_sums<<<1, 256, 0, stream>>>(bsum, boff, nb);
    scan_fixup<<<nb, 256, 0, stream>>>(rowptr, boff, cursor);
    fill_csr<<<(EE + 255) / 256, 256, 0, stream>>>(ei, cursor, csr_src);

    const int dims[4] = {768, 512, 256, 128};

    for (int l = 0; l < 3; ++l) {
        int K = dims[l], D = dims[l + 1];

        dim3 gg(D / 128, MP / 128);
        if (l == 0)
            gemm_split3<0><<<gg, 256, 0, stream>>>((const unsigned int*)x, Wh[0], Wl[0],
                                                   hw, dis, K, D);
        else
            gemm_split3<1><<<gg, 256, 0, stream>>>(agg, Wh[l], Wl[l], hw, dis, K, D);

        int tpn = D / 8;
        int npb = 256 / tpn;
        agg_gather<<<(NN + npb - 1) / npb, 256, 0, stream>>>(hw, (float*)agg, rowptr, csr_src,
                                                             dis, bbv[l], D);

        fill_f32<<<(2 * D + 255) / 256, 256, 0, stream>>>(stats, 2 * D, 0.0f);
        bn_stats<<<dim3((D + 255) / 256, 256), 256, 0, stream>>>((const float*)agg, stats, D);
        if (l < 2) {
            size_t tot = (size_t)NN * D;
            bn_apply<<<(int)((tot + 255) / 256), 256, 0, stream>>>(agg, stats, gm[l], bt[l], D);
        } else {
            bn_coef<<<1, 128, 0, stream>>>(stats, gm[2], bt[2], c1, c2, 128);
        }
    }

    find_starts<<<nb, 256, 0, stream>>>(batch, start);
    pool_bn<<<BB, 128, 0, stream>>>((const float*)agg, start, c1, c2, pool);
    classifier_kernel<<<1, 256, 0, stream>>>(pool, Wc1, bc1, gc, bec, Wc2, bc2, out);
}

// Round 9
// 820.034 us; speedup vs baseline: 1.5563x; 1.2345x over previous
//
#include <hip/hip_runtime.h>
#include <cstddef>

#define NN 50000
#define EE 400000
#define BB 64
#define MP 50048            // padded rows: 391 * 128
#define BN_EPS 1e-5f
#define PSEG 32             // pooling segments per graph

typedef __attribute__((ext_vector_type(8))) short s16x8;
typedef __attribute__((ext_vector_type(4))) float f32x4;
typedef __attribute__((ext_vector_type(8))) _Float16 f16x8;

#define GLOAD_LDS16(g, l) __builtin_amdgcn_global_load_lds( \
    (const __attribute__((address_space(1))) void*)(g),     \
    (__attribute__((address_space(3))) void*)(l), 16, 0, 0)

// ---------------- utility ----------------
__global__ void fill_f32(float* __restrict__ p, int n, float v) {
    int i = blockIdx.x * blockDim.x + threadIdx.x;
    if (i < n) p[i] = v;
}

__global__ void fill_i32(int* __restrict__ p, int n, int v) {
    int i = blockIdx.x * blockDim.x + threadIdx.x;
    if (i < n) p[i] = v;
}

__global__ void deg_edges(const int* __restrict__ ei, int* __restrict__ deg) {
    int e = blockIdx.x * blockDim.x + threadIdx.x;
    if (e < EE) atomicAdd(&deg[ei[EE + e]], 1);
}

// W [K][N] fp32 -> two bf16 planes Wh/Wl [N][K] (hi = truncate, lo = residual)
__global__ void cvt_wt_planes(const float* __restrict__ W,
                              unsigned short* __restrict__ Wh,
                              unsigned short* __restrict__ Wl,
                              int K, int N) {
    int i = blockIdx.x * blockDim.x + threadIdx.x;
    if (i >= K * N) return;
    int k = i / N, n = i % N;
    float f = W[i];
    unsigned int fb = __float_as_uint(f);
    unsigned int hif = fb & 0xFFFF0000u;
    float lo = f - __uint_as_float(hif);
    Wh[(size_t)n * K + k] = (unsigned short)(hif >> 16);
    Wl[(size_t)n * K + k] = (unsigned short)(__float_as_uint(lo) >> 16);
}

// ---------------- CSR build (scan; rsqrt fused) ----------------
__global__ __launch_bounds__(256) void scan_block(const int* __restrict__ deg,
                                                  int* __restrict__ rowptr,
                                                  int* __restrict__ bsum,
                                                  float* __restrict__ dis) {
    __shared__ int tmp[256];
    int tid = threadIdx.x;
    int i = blockIdx.x * 256 + tid;
    int v = (i < NN) ? deg[i] : 0;
    if (i < NN) dis[i] = rsqrtf((float)v + 1.0f);
    tmp[tid] = v;
    __syncthreads();
#pragma unroll
    for (int off = 1; off < 256; off <<= 1) {
        int t = (tid >= off) ? tmp[tid - off] : 0;
        __syncthreads();
        tmp[tid] += t;
        __syncthreads();
    }
    if (i < NN) rowptr[i] = tmp[tid] - v;
    if (tid == 255) bsum[blockIdx.x] = tmp[255];
}

__global__ __launch_bounds__(256) void scan_sums(const int* __restrict__ bsum,
                                                 int* __restrict__ boff, int nb) {
    __shared__ int tmp[256];
    int tid = threadIdx.x;
    int v = (tid < nb) ? bsum[tid] : 0;
    tmp[tid] = v;
    __syncthreads();
#pragma unroll
    for (int off = 1; off < 256; off <<= 1) {
        int t = (tid >= off) ? tmp[tid - off] : 0;
        __syncthreads();
        tmp[tid] += t;
        __syncthreads();
    }
    boff[tid] = tmp[tid] - v;
}

__global__ void scan_fixup(int* __restrict__ rowptr, const int* __restrict__ boff,
                           int* __restrict__ cursor) {
    int i = blockIdx.x * blockDim.x + threadIdx.x;
    if (i < NN) {
        int v = rowptr[i] + boff[i >> 8];
        rowptr[i] = v;
        cursor[i] = v;
    }
    if (i == 0) rowptr[NN] = EE;
}

__global__ void fill_csr(const int* __restrict__ ei, int* __restrict__ cursor,
                         int* __restrict__ csr_src) {
    int e = blockIdx.x * blockDim.x + threadIdx.x;
    if (e >= EE) return;
    int s = ei[e];
    int t = ei[EE + e];
    int pos = atomicAdd(&cursor[t], 1);
    csr_src[pos] = s;
}

// ---------------- split helpers (mask/shift only — hardware-validated r5-r8) ------
static __device__ __forceinline__ void unpack_pk(const uint4& u0, const uint4& u1,
                                                 s16x8& h, s16x8& l) {
    unsigned int p[8] = {u0.x, u0.y, u0.z, u0.w, u1.x, u1.y, u1.z, u1.w};
    union { s16x8 v; unsigned int u[4]; } H, L;
#pragma unroll
    for (int k = 0; k < 4; ++k) {
        H.u[k] = (p[2 * k + 1] & 0xFFFF0000u) | (p[2 * k] >> 16);
        L.u[k] = (p[2 * k + 1] << 16) | (p[2 * k] & 0xFFFFu);
    }
    h = H.v; l = L.v;
}

static __device__ __forceinline__ void unpack_f32(const uint4& u0, const uint4& u1,
                                                  s16x8& h, s16x8& l) {
    unsigned int e[8] = {u0.x, u0.y, u0.z, u0.w, u1.x, u1.y, u1.z, u1.w};
    unsigned int hi[8], lo[8];
#pragma unroll
    for (int j = 0; j < 8; ++j) {
        hi[j] = e[j] & 0xFFFF0000u;
        float lf = __uint_as_float(e[j]) - __uint_as_float(hi[j]);
        lo[j] = __float_as_uint(lf);
    }
    union { s16x8 v; unsigned int u[4]; } H, L;
#pragma unroll
    for (int k = 0; k < 4; ++k) {
        H.u[k] = (hi[2 * k + 1]) | (hi[2 * k] >> 16);
        L.u[k] = (lo[2 * k + 1] & 0xFFFF0000u) | (lo[2 * k] >> 16);
    }
    h = H.v; l = L.v;
}

// ------ split-bf16 3-MFMA GEMM: C[MP,N] = dis[row] * (A[MP,K] @ W[N,K]^T), fp16 out --
template <int AMODE>
__global__ __launch_bounds__(256) void gemm_split3(const unsigned int* __restrict__ A,
                                                   const unsigned short* __restrict__ Bh,
                                                   const unsigned short* __restrict__ Bl,
                                                   _Float16* __restrict__ C,
                                                   const float* __restrict__ dis,
                                                   int K, int N) {
    __shared__ unsigned int As[128 * 32];     // 16 KB  [row][k-u32]
    __shared__ unsigned short Bsh[128 * 32];  // 8 KB   [col][k]
    __shared__ unsigned short Bsl[128 * 32];  // 8 KB
    const int tid = threadIdx.x;
    const int w  = tid >> 6;
    const int lw = tid & 63;
    const int lo = lw & 15;
    const int hi = lw >> 4;
    const int wr = w >> 1, wc = w & 1;
    const int rowBase = blockIdx.y * 128;
    const int colBase = blockIdx.x * 128;

    const int arow = w * 8 + (lw >> 3);
    const int acol = (lw & 7) * 4;
    const int brow = w * 16 + (lw >> 2);
    const int bcol = (lw & 3) * 8;

    f32x4 acc[4][4];
#pragma unroll
    for (int m = 0; m < 4; ++m)
#pragma unroll
        for (int n = 0; n < 4; ++n) acc[m][n] = (f32x4){0.f, 0.f, 0.f, 0.f};

    for (int k0 = 0; k0 < K; k0 += 32) {
#pragma unroll
        for (int i = 0; i < 4; ++i) {
            int gr = rowBase + i * 32 + arow;
            gr = (gr < NN) ? gr : (NN - 1);
            GLOAD_LDS16(A + (size_t)gr * K + k0 + acol, (char*)As + i * 4096 + w * 1024);
        }
#pragma unroll
        for (int j = 0; j < 2; ++j) {
            int gc = colBase + j * 64 + brow;
            GLOAD_LDS16(Bh + (size_t)gc * K + k0 + bcol, (char*)Bsh + j * 4096 + w * 1024);
            GLOAD_LDS16(Bl + (size_t)gc * K + k0 + bcol, (char*)Bsl + j * 4096 + w * 1024);
        }
        __syncthreads();

        s16x8 ah[4], al[4], bh[4], bl[4];
#pragma unroll
        for (int m = 0; m < 4; ++m) {
            int r = wr * 64 + m * 16 + lo;
            uint4 u0 = *(const uint4*)&As[r * 32 + hi * 8];
            uint4 u1 = *(const uint4*)&As[r * 32 + hi * 8 + 4];
            if (AMODE == 0) unpack_f32(u0, u1, ah[m], al[m]);
            else            unpack_pk(u0, u1, ah[m], al[m]);
        }
#pragma unroll
        for (int n = 0; n < 4; ++n) {
            int r = wc * 64 + n * 16 + lo;
            bh[n] = *(const s16x8*)&Bsh[r * 32 + hi * 8];
            bl[n] = *(const s16x8*)&Bsl[r * 32 + hi * 8];
        }
#pragma unroll
        for (int m = 0; m < 4; ++m)
#pragma unroll
            for (int n = 0; n < 4; ++n) {
                acc[m][n] = __builtin_amdgcn_mfma_f32_16x16x32_bf16(ah[m], bh[n], acc[m][n], 0, 0, 0);
                acc[m][n] = __builtin_amdgcn_mfma_f32_16x16x32_bf16(ah[m], bl[n], acc[m][n], 0, 0, 0);
                acc[m][n] = __builtin_amdgcn_mfma_f32_16x16x32_bf16(al[m], bh[n], acc[m][n], 0, 0, 0);
            }
        __syncthreads();
    }

#pragma unroll
    for (int m = 0; m < 4; ++m) {
        int row0 = rowBase + wr * 64 + m * 16 + hi * 4;
#pragma unroll
        for (int j = 0; j < 4; ++j) {
            int r = row0 + j;
            float ds = dis[(r < NN) ? r : (NN - 1)];
#pragma unroll
            for (int n = 0; n < 4; ++n) {
                int col = colBase + wc * 64 + n * 16 + lo;
                C[(size_t)r * N + col] = (_Float16)(ds * acc[m][n][j]);
            }
        }
    }
}

// ------ gather aggregation: fp16 hws in, fp32 agg out, 4-edge unroll ------
__global__ __launch_bounds__(256) void agg_gather(const _Float16* __restrict__ hws,
                                                  float* __restrict__ agg,
                                                  const int* __restrict__ rowptr,
                                                  const int* __restrict__ csr_src,
                                                  const float* __restrict__ dis,
                                                  const float* __restrict__ bias,
                                                  int D) {
    const int tpn = D >> 3;                  // threads per node (8 ch each)
    const int npb = 256 / tpn;
    const int local = threadIdx.x / tpn;
    const int lane = threadIdx.x % tpn;
    const int n = blockIdx.x * npb + local;
    if (n >= NN) return;
    const int dq = lane * 8;

    f16x8 sv = *(const f16x8*)&hws[(size_t)n * D + dq];
    float a[8];
#pragma unroll
    for (int j = 0; j < 8; ++j) a[j] = (float)sv[j];

    int e0 = rowptr[n], e1 = rowptr[n + 1];
    int e = e0;
    for (; e + 4 <= e1; e += 4) {
        int s0 = csr_src[e + 0];
        int s1 = csr_src[e + 1];
        int s2 = csr_src[e + 2];
        int s3 = csr_src[e + 3];
        f16x8 v0 = *(const f16x8*)&hws[(size_t)s0 * D + dq];
        f16x8 v1 = *(const f16x8*)&hws[(size_t)s1 * D + dq];
        f16x8 v2 = *(const f16x8*)&hws[(size_t)s2 * D + dq];
        f16x8 v3 = *(const f16x8*)&hws[(size_t)s3 * D + dq];
#pragma unroll
        for (int j = 0; j < 8; ++j)
            a[j] += ((float)v0[j] + (float)v1[j]) + ((float)v2[j] + (float)v3[j]);
    }
    for (; e < e1; ++e) {
        int s = csr_src[e];
        f16x8 v = *(const f16x8*)&hws[(size_t)s * D + dq];
#pragma unroll
        for (int j = 0; j < 8; ++j) a[j] += (float)v[j];
    }

    float din = dis[n];
    f32x4 o0, o1;
#pragma unroll
    for (int j = 0; j < 4; ++j) o0[j] = din * a[j] + bias[dq + j];
#pragma unroll
    for (int j = 0; j < 4; ++j) o1[j] = din * a[4 + j] + bias[dq + 4 + j];
    *(f32x4*)&agg[(size_t)n * D + dq] = o0;
    *(f32x4*)&agg[(size_t)n * D + dq + 4] = o1;
}

// ---------------- batchnorm stats (column-striped, validated) ----------------
__global__ void bn_stats(const float* __restrict__ h, float* __restrict__ stats, int D) {
    int d = blockIdx.x * blockDim.x + threadIdx.x;
    if (d >= D) return;
    float s = 0.f, ss = 0.f;
    for (int n = blockIdx.y; n < NN; n += gridDim.y) {
        float v = h[(size_t)n * D + d];
        s += v;
        ss += v * v;
    }
    atomicAdd(&stats[d], s);
    atomicAdd(&stats[D + d], ss);
}

// ---------------- batchnorm apply (relu + split-pack; layers 0,1) ----------------
__global__ void bn_apply(unsigned int* __restrict__ buf,
                         const float* __restrict__ stats,
                         const float* __restrict__ gamma, const float* __restrict__ beta,
                         int D) {
    size_t i = (size_t)blockIdx.x * blockDim.x + threadIdx.x;
    if (i >= (size_t)NN * D) return;
    int d = (int)(i % (size_t)D);
    float mean = stats[d] * (1.0f / NN);
    float var  = stats[D + d] * (1.0f / NN) - mean * mean;
    float f = (__uint_as_float(buf[i]) - mean) * rsqrtf(var + BN_EPS) * gamma[d] + beta[d];
    f = fmaxf(f, 0.f);
    unsigned int fb = __float_as_uint(f);
    unsigned int hif = fb & 0xFFFF0000u;
    float lf = f - __uint_as_float(hif);
    buf[i] = hif | (__float_as_uint(lf) >> 16);
}

// ---------------- layer-2 BN coefficients ----------------
__global__ void bn_coef(const float* __restrict__ stats,
                        const float* __restrict__ gamma, const float* __restrict__ beta,
                        float* __restrict__ c1, float* __restrict__ c2, int D) {
    int d = blockIdx.x * blockDim.x + threadIdx.x;
    if (d >= D) return;
    float mean = stats[d] * (1.0f / NN);
    float var  = stats[D + d] * (1.0f / NN) - mean * mean;
    float r = rsqrtf(var + BN_EPS) * gamma[d];
    c1[d] = r;
    c2[d] = beta[d] - mean * r;
}

// ---------------- pooling (two-stage segmented, BN affine fused) ----------------
__global__ void find_starts(const int* __restrict__ batch, int* __restrict__ start) {
    int n = blockIdx.x * blockDim.x + threadIdx.x;
    if (n >= NN) return;
    int bc = batch[n];
    int bp = (n == 0) ? -1 : batch[n - 1];
    for (int g = bp + 1; g <= bc; ++g) start[g] = n;
    if (n == NN - 1) {
        for (int g = bc + 1; g <= BB; ++g) start[g] = NN;
    }
}

// stage 1: grid (BB, PSEG), 128 threads; partials: part[(b*PSEG+seg)*256 + {d | 128+d}]
__global__ void pool_part(const float* __restrict__ h, const int* __restrict__ start,
                          const float* __restrict__ c1, const float* __restrict__ c2,
                          float* __restrict__ part) {
    int b = blockIdx.x;
    int seg = blockIdx.y;
    int d = threadIdx.x;
    int s0 = start[b], s1 = start[b + 1];
    int len = s1 - s0;
    int a = s0 + (int)((long long)len * seg / PSEG);
    int e = s0 + (int)((long long)len * (seg + 1) / PSEG);
    float a1 = c1[d], a2 = c2[d];
    float sum = 0.f;
    float mx = -3.402823466e+38f;
    for (int n = a; n < e; ++n) {
        float v = a1 * h[(size_t)n * 128 + d] + a2;
        sum += v;
        mx = fmaxf(mx, v);
    }
    part[(size_t)(b * PSEG + seg) * 256 + d] = sum;
    part[(size_t)(b * PSEG + seg) * 256 + 128 + d] = mx;
}

// stage 2: grid BB, 128 threads
__global__ void pool_reduce(const float* __restrict__ part, const int* __restrict__ start,
                            float* __restrict__ pool) {
    int b = blockIdx.x;
    int d = threadIdx.x;
    float sum = 0.f;
    float mx = -3.402823466e+38f;
    for (int s = 0; s < PSEG; ++s) {
        sum += part[(size_t)(b * PSEG + s) * 256 + d];
        mx = fmaxf(mx, part[(size_t)(b * PSEG + s) * 256 + 128 + d]);
    }
    float cnt = fmaxf((float)(start[b + 1] - start[b]), 1.0f);
    pool[b * 256 + d] = sum / cnt;
    pool[b * 256 + 128 + d] = mx;
}

// ---------------- classifier (single block, fp32) ----------------
__global__ __launch_bounds__(256) void classifier_kernel(
        const float* __restrict__ pool,
        const float* __restrict__ Wc1, const float* __restrict__ bc1,
        const float* __restrict__ gc, const float* __restrict__ bec,
        const float* __restrict__ Wc2, const float* __restrict__ bc2,
        float* __restrict__ out) {
    __shared__ float hc[64][65];
    __shared__ float cmean[64];
    __shared__ float crstd[64];
    int tid = threadIdx.x;

    for (int i = tid; i < 64 * 64; i += 256) {
        int r = i / 64, c = i % 64;
        float acc = bc1[c];
        for (int k = 0; k < 256; ++k)
            acc += pool[r * 256 + k] * Wc1[k * 64 + c];
        hc[r][c] = fmaxf(acc, 0.f);
    }
    __syncthreads();

    if (tid < 64) {
        float s = 0.f, ss = 0.f;
        for (int r = 0; r < 64; ++r) {
            float v = hc[r][tid];
            s += v;
            ss += v * v;
        }
        float m = s * (1.0f / 64.0f);
        float var = ss * (1.0f / 64.0f) - m * m;
        cmean[tid] = m;
        crstd[tid] = rsqrtf(var + BN_EPS);
    }
    __syncthreads();

    if (tid < 128) {
        int r = tid / 2, k = tid % 2;
        float acc = bc2[k];
        for (int c = 0; c < 64; ++c) {
            float v = (hc[r][c] - cmean[c]) * crstd[c] * gc[c] + bec[c];
            acc += v * Wc2[c * 2 + k];
        }
        out[r * 2 + k] = acc;
    }
}

// ---------------- launch ----------------
extern "C" void kernel_launch(void* const* d_in, const int* in_sizes, int n_in,
                              void* d_out, int out_size, void* d_ws, size_t ws_size,
                              hipStream_t stream) {
    const float* x     = (const float*)d_in[0];
    const int*   ei    = (const int*)d_in[1];
    const int*   batch = (const int*)d_in[2];
    const float* W[3]  = {(const float*)d_in[3], (const float*)d_in[7], (const float*)d_in[11]};
    const float* bbv[3] = {(const float*)d_in[4], (const float*)d_in[8], (const float*)d_in[12]};
    const float* gm[3] = {(const float*)d_in[5], (const float*)d_in[9], (const float*)d_in[13]};
    const float* bt[3] = {(const float*)d_in[6], (const float*)d_in[10], (const float*)d_in[14]};
    const float* Wc1 = (const float*)d_in[15];
    const float* bc1 = (const float*)d_in[16];
    const float* gc  = (const float*)d_in[17];
    const float* bec = (const float*)d_in[18];
    const float* Wc2 = (const float*)d_in[19];
    const float* bc2 = (const float*)d_in[20];
    float* out = (float*)d_out;

    // workspace carve-up
    char* p = (char*)d_ws;
    _Float16* hw = (_Float16*)p; p += (size_t)MP * 512 * 2;           // fp16 dis-scaled GEMM out
    unsigned int* agg = (unsigned int*)p; p += (size_t)NN * 512 * 4;  // agg f32 / h packed
    unsigned short* Wh[3];
    unsigned short* Wl[3];
    Wh[0] = (unsigned short*)p; p += (size_t)512 * 768 * 2;
    Wl[0] = (unsigned short*)p; p += (size_t)512 * 768 * 2;
    Wh[1] = (unsigned short*)p; p += (size_t)256 * 512 * 2;
    Wl[1] = (unsigned short*)p; p += (size_t)256 * 512 * 2;
    Wh[2] = (unsigned short*)p; p += (size_t)128 * 256 * 2;
    Wl[2] = (unsigned short*)p; p += (size_t)128 * 256 * 2;
    float* dis   = (float*)p; p += (size_t)NN * 4;
    float* stats = (float*)p; p += 1024 * 4;     // [0:2D) sums; c1 at +512, c2 at +640
    float* pool  = (float*)p; p += (size_t)BB * 256 * 4;
    float* part  = (float*)p; p += (size_t)BB * PSEG * 256 * 4;   // 2 MB partials
    int* deg_i   = (int*)p; p += (size_t)NN * 4;
    int* rowptr  = (int*)p; p += (size_t)(NN + 1) * 4;
    int* cursor  = (int*)p; p += (size_t)NN * 4;
    int* bsum    = (int*)p; p += 256 * 4;
    int* boff    = (int*)p; p += 256 * 4;
    int* csr_src = (int*)p; p += (size_t)EE * 4;
    int* start   = (int*)p; p += (BB + 1) * 4;
    float* c1 = stats + 512;
    float* c2 = stats + 640;

    const int nb = (NN + 255) / 256;

    // weight plane split (tiny)
    cvt_wt_planes<<<(768 * 512 + 255) / 256, 256, 0, stream>>>(W[0], Wh[0], Wl[0], 768, 512);
    cvt_wt_planes<<<(512 * 256 + 255) / 256, 256, 0, stream>>>(W[1], Wh[1], Wl[1], 512, 256);
    cvt_wt_planes<<<(256 * 128 + 255) / 256, 256, 0, stream>>>(W[2], Wh[2], Wl[2], 256, 128);

    // degree + dis + CSR
    fill_i32<<<nb, 256, 0, stream>>>(deg_i, NN, 0);
    deg_edges<<<(EE + 255) / 256, 256, 0, stream>>>(ei, deg_i);
    scan_block<<<nb, 256, 0, stream>>>(deg_i, rowptr, bsum, dis);
    scan_sums<<<1, 256, 0, stream>>>(bsum, boff, nb);
    scan_fixup<<<nb, 256, 0, stream>>>(rowptr, boff, cursor);
    fill_csr<<<(EE + 255) / 256, 256, 0, stream>>>(ei, cursor, csr_src);

    const int dims[4] = {768, 512, 256, 128};

    for (int l = 0; l < 3; ++l) {
        int K = dims[l], D = dims[l + 1];

        dim3 gg(D / 128, MP / 128);
        if (l == 0)
            gemm_split3<0><<<gg, 256, 0, stream>>>((const unsigned int*)x, Wh[0], Wl[0],
                                                   hw, dis, K, D);
        else
            gemm_split3<1><<<gg, 256, 0, stream>>>(agg, Wh[l], Wl[l], hw, dis, K, D);

        int tpn = D / 8;
        int npb = 256 / tpn;
        agg_gather<<<(NN + npb - 1) / npb, 256, 0, stream>>>(hw, (float*)agg, rowptr, csr_src,
                                                             dis, bbv[l], D);

        fill_f32<<<(2 * D + 255) / 256, 256, 0, stream>>>(stats, 2 * D, 0.0f);
        bn_stats<<<dim3((D + 255) / 256, 256), 256, 0, stream>>>((const float*)agg, stats, D);
        if (l < 2) {
            size_t tot = (size_t)NN * D;
            bn_apply<<<(int)((tot + 255) / 256), 256, 0, stream>>>(agg, stats, gm[l], bt[l], D);
        } else {
            bn_coef<<<1, 128, 0, stream>>>(stats, gm[2], bt[2], c1, c2, 128);
        }
    }

    find_starts<<<nb, 256, 0, stream>>>(batch, start);
    dim3 pg(BB, PSEG);
    pool_part<<<pg, 128, 0, stream>>>((const float*)agg, start, c1, c2, part);
    pool_reduce<<<BB, 128, 0, stream>>>(part, start, pool);
    classifier_kernel<<<1, 256, 0, stream>>>(pool, Wc1, bc1, gc, bec, Wc2, bc2, out);
}

// Round 11
// 807.973 us; speedup vs baseline: 1.5795x; 1.0149x over previous
//
#include <hip/hip_runtime.h>
#include <cstddef>

#define NN 50000
#define EE 400000
#define BB 64
#define MP 50048            // padded rows: 391 * 128
#define BN_EPS 1e-5f
#define PSEG 32             // pooling segments per graph

typedef __attribute__((ext_vector_type(8))) short s16x8;
typedef __attribute__((ext_vector_type(4))) float f32x4;
typedef __attribute__((ext_vector_type(8))) _Float16 f16x8;

#define GLOAD_LDS16(g, l) __builtin_amdgcn_global_load_lds( \
    (const __attribute__((address_space(1))) void*)(g),     \
    (__attribute__((address_space(3))) void*)(l), 16, 0, 0)

// ---------------- utility ----------------
__global__ void fill_f32(float* __restrict__ p, int n, float v) {
    int i = blockIdx.x * blockDim.x + threadIdx.x;
    if (i < n) p[i] = v;
}

__global__ void fill_i32(int* __restrict__ p, int n, int v) {
    int i = blockIdx.x * blockDim.x + threadIdx.x;
    if (i < n) p[i] = v;
}

__global__ void deg_edges(const int* __restrict__ ei, int* __restrict__ deg) {
    int e = blockIdx.x * blockDim.x + threadIdx.x;
    if (e < EE) atomicAdd(&deg[ei[EE + e]], 1);
}

// W [K][N] fp32 -> two bf16 planes Wh/Wl [N][K] (hi = truncate, lo = residual)
__global__ void cvt_wt_planes(const float* __restrict__ W,
                              unsigned short* __restrict__ Wh,
                              unsigned short* __restrict__ Wl,
                              int K, int N) {
    int i = blockIdx.x * blockDim.x + threadIdx.x;
    if (i >= K * N) return;
    int k = i / N, n = i % N;
    float f = W[i];
    unsigned int fb = __float_as_uint(f);
    unsigned int hif = fb & 0xFFFF0000u;
    float lo = f - __uint_as_float(hif);
    Wh[(size_t)n * K + k] = (unsigned short)(hif >> 16);
    Wl[(size_t)n * K + k] = (unsigned short)(__float_as_uint(lo) >> 16);
}

// ---------------- CSR build (scan; rsqrt fused) ----------------
__global__ __launch_bounds__(256) void scan_block(const int* __restrict__ deg,
                                                  int* __restrict__ rowptr,
                                                  int* __restrict__ bsum,
                                                  float* __restrict__ dis) {
    __shared__ int tmp[256];
    int tid = threadIdx.x;
    int i = blockIdx.x * 256 + tid;
    int v = (i < NN) ? deg[i] : 0;
    if (i < NN) dis[i] = rsqrtf((float)v + 1.0f);
    tmp[tid] = v;
    __syncthreads();
#pragma unroll
    for (int off = 1; off < 256; off <<= 1) {
        int t = (tid >= off) ? tmp[tid - off] : 0;
        __syncthreads();
        tmp[tid] += t;
        __syncthreads();
    }
    if (i < NN) rowptr[i] = tmp[tid] - v;
    if (tid == 255) bsum[blockIdx.x] = tmp[255];
}

__global__ __launch_bounds__(256) void scan_sums(const int* __restrict__ bsum,
                                                 int* __restrict__ boff, int nb) {
    __shared__ int tmp[256];
    int tid = threadIdx.x;
    int v = (tid < nb) ? bsum[tid] : 0;
    tmp[tid] = v;
    __syncthreads();
#pragma unroll
    for (int off = 1; off < 256; off <<= 1) {
        int t = (tid >= off) ? tmp[tid - off] : 0;
        __syncthreads();
        tmp[tid] += t;
        __syncthreads();
    }
    boff[tid] = tmp[tid] - v;
}

__global__ void scan_fixup(int* __restrict__ rowptr, const int* __restrict__ boff,
                           int* __restrict__ cursor) {
    int i = blockIdx.x * blockDim.x + threadIdx.x;
    if (i < NN) {
        int v = rowptr[i] + boff[i >> 8];
        rowptr[i] = v;
        cursor[i] = v;
    }
    if (i == 0) rowptr[NN] = EE;
}

__global__ void fill_csr(const int* __restrict__ ei, int* __restrict__ cursor,
                         int* __restrict__ csr_src) {
    int e = blockIdx.x * blockDim.x + threadIdx.x;
    if (e >= EE) return;
    int s = ei[e];
    int t = ei[EE + e];
    int pos = atomicAdd(&cursor[t], 1);
    csr_src[pos] = s;
}

// ---------------- split helpers (mask/shift only — hardware-validated r5-r9) ------
static __device__ __forceinline__ void unpack_pk(const uint4& u0, const uint4& u1,
                                                 s16x8& h, s16x8& l) {
    unsigned int p[8] = {u0.x, u0.y, u0.z, u0.w, u1.x, u1.y, u1.z, u1.w};
    union { s16x8 v; unsigned int u[4]; } H, L;
#pragma unroll
    for (int k = 0; k < 4; ++k) {
        H.u[k] = (p[2 * k + 1] & 0xFFFF0000u) | (p[2 * k] >> 16);
        L.u[k] = (p[2 * k + 1] << 16) | (p[2 * k] & 0xFFFFu);
    }
    h = H.v; l = L.v;
}

static __device__ __forceinline__ void unpack_f32(const uint4& u0, const uint4& u1,
                                                  s16x8& h, s16x8& l) {
    unsigned int e[8] = {u0.x, u0.y, u0.z, u0.w, u1.x, u1.y, u1.z, u1.w};
    unsigned int hi[8], lo[8];
#pragma unroll
    for (int j = 0; j < 8; ++j) {
        hi[j] = e[j] & 0xFFFF0000u;
        float lf = __uint_as_float(e[j]) - __uint_as_float(hi[j]);
        lo[j] = __float_as_uint(lf);
    }
    union { s16x8 v; unsigned int u[4]; } H, L;
#pragma unroll
    for (int k = 0; k < 4; ++k) {
        H.u[k] = (hi[2 * k + 1]) | (hi[2 * k] >> 16);
        L.u[k] = (lo[2 * k + 1] & 0xFFFF0000u) | (lo[2 * k] >> 16);
    }
    h = H.v; l = L.v;
}

// ------ split-bf16 3-MFMA GEMM, DOUBLE-BUFFERED (T3 minimum 2-phase) ------
// C[MP,N] = dis[row] * (A[MP,K] @ W[N,K]^T), fp16 out. B pre-split bf16 planes.
// AMODE 0: A fp32 (in-kernel split). AMODE 1: A packed u32.
// Pipeline: STAGE(next) issued BEFORE compute(cur); raw s_barrier + explicit vmcnt(0)
// at iteration end (no __syncthreads -> no forced early drain).
template <int AMODE>
__global__ __launch_bounds__(256) void gemm_split3(const unsigned int* __restrict__ A,
                                                   const unsigned short* __restrict__ Bh,
                                                   const unsigned short* __restrict__ Bl,
                                                   _Float16* __restrict__ C,
                                                   const float* __restrict__ dis,
                                                   int K, int N) {
    __shared__ unsigned int As[2][128 * 32];     // 2 x 16 KB
    __shared__ unsigned short Bsh[2][128 * 32];  // 2 x 8 KB
    __shared__ unsigned short Bsl[2][128 * 32];  // 2 x 8 KB  (total 64 KB)
    const int tid = threadIdx.x;
    const int w  = tid >> 6;
    const int lw = tid & 63;
    const int lo = lw & 15;
    const int hi = lw >> 4;
    const int wr = w >> 1, wc = w & 1;
    const int rowBase = blockIdx.y * 128;
    const int colBase = blockIdx.x * 128;

    const int arow = w * 8 + (lw >> 3);
    const int acol = (lw & 7) * 4;
    const int brow = w * 16 + (lw >> 2);
    const int bcol = (lw & 3) * 8;

    f32x4 acc[4][4];
#pragma unroll
    for (int m = 0; m < 4; ++m)
#pragma unroll
        for (int n = 0; n < 4; ++n) acc[m][n] = (f32x4){0.f, 0.f, 0.f, 0.f};

#define STAGE(buf, k0s) do {                                                        \
    _Pragma("unroll")                                                               \
    for (int i_ = 0; i_ < 4; ++i_) {                                                \
        int gr_ = rowBase + i_ * 32 + arow;                                         \
        gr_ = (gr_ < NN) ? gr_ : (NN - 1);                                          \
        GLOAD_LDS16(A + (size_t)gr_ * K + (k0s) + acol,                             \
                    (char*)&As[buf][0] + i_ * 4096 + w * 1024);                     \
    }                                                                               \
    _Pragma("unroll")                                                               \
    for (int j_ = 0; j_ < 2; ++j_) {                                                \
        int gc_ = colBase + j_ * 64 + brow;                                         \
        GLOAD_LDS16(Bh + (size_t)gc_ * K + (k0s) + bcol,                            \
                    (char*)&Bsh[buf][0] + j_ * 4096 + w * 1024);                    \
        GLOAD_LDS16(Bl + (size_t)gc_ * K + (k0s) + bcol,                            \
                    (char*)&Bsl[buf][0] + j_ * 4096 + w * 1024);                    \
    }                                                                               \
} while (0)

    // prologue: fill buffer 0
    STAGE(0, 0);
    asm volatile("s_waitcnt vmcnt(0)" ::: "memory");
    __builtin_amdgcn_s_barrier();

    const int nt = K >> 5;
    int cur = 0;
    for (int t = 0; t < nt; ++t) {
        if (t + 1 < nt) STAGE(cur ^ 1, (t + 1) << 5);   // prefetch next tile (async)

        s16x8 ah[4], al[4], bh[4], bl[4];
#pragma unroll
        for (int m = 0; m < 4; ++m) {
            int r = wr * 64 + m * 16 + lo;
            uint4 u0 = *(const uint4*)&As[cur][r * 32 + hi * 8];
            uint4 u1 = *(const uint4*)&As[cur][r * 32 + hi * 8 + 4];
            if (AMODE == 0) unpack_f32(u0, u1, ah[m], al[m]);
            else            unpack_pk(u0, u1, ah[m], al[m]);
        }
#pragma unroll
        for (int n = 0; n < 4; ++n) {
            int r = wc * 64 + n * 16 + lo;
            bh[n] = *(const s16x8*)&Bsh[cur][r * 32 + hi * 8];
            bl[n] = *(const s16x8*)&Bsl[cur][r * 32 + hi * 8];
        }
#pragma unroll
        for (int m = 0; m < 4; ++m)
#pragma unroll
            for (int n = 0; n < 4; ++n) {
                acc[m][n] = __builtin_amdgcn_mfma_f32_16x16x32_bf16(ah[m], bh[n], acc[m][n], 0, 0, 0);
                acc[m][n] = __builtin_amdgcn_mfma_f32_16x16x32_bf16(ah[m], bl[n], acc[m][n], 0, 0, 0);
                acc[m][n] = __builtin_amdgcn_mfma_f32_16x16x32_bf16(al[m], bh[n], acc[m][n], 0, 0, 0);
            }

        asm volatile("s_waitcnt vmcnt(0)" ::: "memory");   // next-tile loads landed
        __builtin_amdgcn_s_barrier();                      // all waves done reading cur
        cur ^= 1;
    }
#undef STAGE

#pragma unroll
    for (int m = 0; m < 4; ++m) {
        int row0 = rowBase + wr * 64 + m * 16 + hi * 4;
#pragma unroll
        for (int j = 0; j < 4; ++j) {
            int r = row0 + j;
            float ds = dis[(r < NN) ? r : (NN - 1)];
#pragma unroll
            for (int n = 0; n < 4; ++n) {
                int col = colBase + wc * 64 + n * 16 + lo;
                C[(size_t)r * N + col] = (_Float16)(ds * acc[m][n][j]);
            }
        }
    }
}

// ------ gather aggregation: fp16 hws in, fp32 agg out, 4-edge unroll (r9-validated) ------
__global__ __launch_bounds__(256) void agg_gather(const _Float16* __restrict__ hws,
                                                  float* __restrict__ agg,
                                                  const int* __restrict__ rowptr,
                                                  const int* __restrict__ csr_src,
                                                  const float* __restrict__ dis,
                                                  const float* __restrict__ bias,
                                                  int D) {
    const int tpn = D >> 3;                  // threads per node (8 ch each)
    const int npb = 256 / tpn;
    const int local = threadIdx.x / tpn;
    const int lane = threadIdx.x % tpn;
    const int n = blockIdx.x * npb + local;
    if (n >= NN) return;
    const int dq = lane * 8;

    f16x8 sv = *(const f16x8*)&hws[(size_t)n * D + dq];
    float a[8];
#pragma unroll
    for (int j = 0; j < 8; ++j) a[j] = (float)sv[j];

    int e0 = rowptr[n], e1 = rowptr[n + 1];
    int e = e0;
    for (; e + 4 <= e1; e += 4) {
        int s0 = csr_src[e + 0];
        int s1 = csr_src[e + 1];
        int s2 = csr_src[e + 2];
        int s3 = csr_src[e + 3];
        f16x8 v0 = *(const f16x8*)&hws[(size_t)s0 * D + dq];
        f16x8 v1 = *(const f16x8*)&hws[(size_t)s1 * D + dq];
        f16x8 v2 = *(const f16x8*)&hws[(size_t)s2 * D + dq];
        f16x8 v3 = *(const f16x8*)&hws[(size_t)s3 * D + dq];
#pragma unroll
        for (int j = 0; j < 8; ++j)
            a[j] += ((float)v0[j] + (float)v1[j]) + ((float)v2[j] + (float)v3[j]);
    }
    for (; e < e1; ++e) {
        int s = csr_src[e];
        f16x8 v = *(const f16x8*)&hws[(size_t)s * D + dq];
#pragma unroll
        for (int j = 0; j < 8; ++j) a[j] += (float)v[j];
    }

    float din = dis[n];
    f32x4 o0, o1;
#pragma unroll
    for (int j = 0; j < 4; ++j) o0[j] = din * a[j] + bias[dq + j];
#pragma unroll
    for (int j = 0; j < 4; ++j) o1[j] = din * a[4 + j] + bias[dq + 4 + j];
    *(f32x4*)&agg[(size_t)n * D + dq] = o0;
    *(f32x4*)&agg[(size_t)n * D + dq + 4] = o1;
}

// ---------------- batchnorm stats (column-striped, validated) ----------------
__global__ void bn_stats(const float* __restrict__ h, float* __restrict__ stats, int D) {
    int d = blockIdx.x * blockDim.x + threadIdx.x;
    if (d >= D) return;
    float s = 0.f, ss = 0.f;
    for (int n = blockIdx.y; n < NN; n += gridDim.y) {
        float v = h[(size_t)n * D + d];
        s += v;
        ss += v * v;
    }
    atomicAdd(&stats[d], s);
    atomicAdd(&stats[D + d], ss);
}

// ---------------- batchnorm apply (relu + split-pack in place; layers 0,1) -------
__global__ void bn_apply(unsigned int* __restrict__ buf,
                         const float* __restrict__ stats,
                         const float* __restrict__ gamma, const float* __restrict__ beta,
                         int D) {
    size_t i = (size_t)blockIdx.x * blockDim.x + threadIdx.x;
    if (i >= (size_t)NN * D) return;
    int d = (int)(i % (size_t)D);
    float mean = stats[d] * (1.0f / NN);
    float var  = stats[D + d] * (1.0f / NN) - mean * mean;
    float f = (__uint_as_float(buf[i]) - mean) * rsqrtf(var + BN_EPS) * gamma[d] + beta[d];
    f = fmaxf(f, 0.f);
    unsigned int fb = __float_as_uint(f);
    unsigned int hif = fb & 0xFFFF0000u;
    float lf = f - __uint_as_float(hif);
    buf[i] = hif | (__float_as_uint(lf) >> 16);
}

// ---------------- layer-2 BN coefficients ----------------
__global__ void bn_coef(const float* __restrict__ stats,
                        const float* __restrict__ gamma, const float* __restrict__ beta,
                        float* __restrict__ c1, float* __restrict__ c2, int D) {
    int d = blockIdx.x * blockDim.x + threadIdx.x;
    if (d >= D) return;
    float mean = stats[d] * (1.0f / NN);
    float var  = stats[D + d] * (1.0f / NN) - mean * mean;
    float r = rsqrtf(var + BN_EPS) * gamma[d];
    c1[d] = r;
    c2[d] = beta[d] - mean * r;
}

// ---------------- pooling (two-stage segmented, BN affine fused; r9-validated) ------
__global__ void find_starts(const int* __restrict__ batch, int* __restrict__ start) {
    int n = blockIdx.x * blockDim.x + threadIdx.x;
    if (n >= NN) return;
    int bc = batch[n];
    int bp = (n == 0) ? -1 : batch[n - 1];
    for (int g = bp + 1; g <= bc; ++g) start[g] = n;
    if (n == NN - 1) {
        for (int g = bc + 1; g <= BB; ++g) start[g] = NN;
    }
}

__global__ void pool_part(const float* __restrict__ h, const int* __restrict__ start,
                          const float* __restrict__ c1, const float* __restrict__ c2,
                          float* __restrict__ part) {
    int b = blockIdx.x;
    int seg = blockIdx.y;
    int d = threadIdx.x;
    int s0 = start[b], s1 = start[b + 1];
    int len = s1 - s0;
    int a = s0 + (int)((long long)len * seg / PSEG);
    int e = s0 + (int)((long long)len * (seg + 1) / PSEG);
    float a1 = c1[d], a2 = c2[d];
    float sum = 0.f;
    float mx = -3.402823466e+38f;
    for (int n = a; n < e; ++n) {
        float v = a1 * h[(size_t)n * 128 + d] + a2;
        sum += v;
        mx = fmaxf(mx, v);
    }
    part[(size_t)(b * PSEG + seg) * 256 + d] = sum;
    part[(size_t)(b * PSEG + seg) * 256 + 128 + d] = mx;
}

__global__ void pool_reduce(const float* __restrict__ part, const int* __restrict__ start,
                            float* __restrict__ pool) {
    int b = blockIdx.x;
    int d = threadIdx.x;
    float sum = 0.f;
    float mx = -3.402823466e+38f;
    for (int s = 0; s < PSEG; ++s) {
        sum += part[(size_t)(b * PSEG + s) * 256 + d];
        mx = fmaxf(mx, part[(size_t)(b * PSEG + s) * 256 + 128 + d]);
    }
    float cnt = fmaxf((float)(start[b + 1] - start[b]), 1.0f);
    pool[b * 256 + d] = sum / cnt;
    pool[b * 256 + 128 + d] = mx;
}

// ---------------- classifier (single block, fp32) ----------------
__global__ __launch_bounds__(256) void classifier_kernel(
        const float* __restrict__ pool,
        const float* __restrict__ Wc1, const float* __restrict__ bc1,
        const float* __restrict__ gc, const float* __restrict__ bec,
        const float* __restrict__ Wc2, const float* __restrict__ bc2,
        float* __restrict__ out) {
    __shared__ float hc[64][65];
    __shared__ float cmean[64];
    __shared__ float crstd[64];
    int tid = threadIdx.x;

    for (int i = tid; i < 64 * 64; i += 256) {
        int r = i / 64, c = i % 64;
        float acc = bc1[c];
        for (int k = 0; k < 256; ++k)
            acc += pool[r * 256 + k] * Wc1[k * 64 + c];
        hc[r][c] = fmaxf(acc, 0.f);
    }
    __syncthreads();

    if (tid < 64) {
        float s = 0.f, ss = 0.f;
        for (int r = 0; r < 64; ++r) {
            float v = hc[r][tid];
            s += v;
            ss += v * v;
        }
        float m = s * (1.0f / 64.0f);
        float var = ss * (1.0f / 64.0f) - m * m;
        cmean[tid] = m;
        crstd[tid] = rsqrtf(var + BN_EPS);
    }
    __syncthreads();

    if (tid < 128) {
        int r = tid / 2, k = tid % 2;
        float acc = bc2[k];
        for (int c = 0; c < 64; ++c) {
            float v = (hc[r][c] - cmean[c]) * crstd[c] * gc[c] + bec[c];
            acc += v * Wc2[c * 2 + k];
        }
        out[r * 2 + k] = acc;
    }
}

// ---------------- launch ----------------
extern "C" void kernel_launch(void* const* d_in, const int* in_sizes, int n_in,
                              void* d_out, int out_size, void* d_ws, size_t ws_size,
                              hipStream_t stream) {
    const float* x     = (const float*)d_in[0];
    const int*   ei    = (const int*)d_in[1];
    const int*   batch = (const int*)d_in[2];
    const float* W[3]  = {(const float*)d_in[3], (const float*)d_in[7], (const float*)d_in[11]};
    const float* bbv[3] = {(const float*)d_in[4], (const float*)d_in[8], (const float*)d_in[12]};
    const float* gm[3] = {(const float*)d_in[5], (const float*)d_in[9], (const float*)d_in[13]};
    const float* bt[3] = {(const float*)d_in[6], (const float*)d_in[10], (const float*)d_in[14]};
    const float* Wc1 = (const float*)d_in[15];
    const float* bc1 = (const float*)d_in[16];
    const float* gc  = (const float*)d_in[17];
    const float* bec = (const float*)d_in[18];
    const float* Wc2 = (const float*)d_in[19];
    const float* bc2 = (const float*)d_in[20];
    float* out = (float*)d_out;

    // workspace carve-up (r9-identical)
    char* p = (char*)d_ws;
    _Float16* hw = (_Float16*)p; p += (size_t)MP * 512 * 2;           // fp16 dis-scaled GEMM out
    unsigned int* agg = (unsigned int*)p; p += (size_t)NN * 512 * 4;  // agg f32 / h packed
    unsigned short* Wh[3];
    unsigned short* Wl[3];
    Wh[0] = (unsigned short*)p; p += (size_t)512 * 768 * 2;
    Wl[0] = (unsigned short*)p; p += (size_t)512 * 768 * 2;
    Wh[1] = (unsigned short*)p; p += (size_t)256 * 512 * 2;
    Wl[1] = (unsigned short*)p; p += (size_t)256 * 512 * 2;
    Wh[2] = (unsigned short*)p; p += (size_t)128 * 256 * 2;
    Wl[2] = (unsigned short*)p; p += (size_t)128 * 256 * 2;
    float* dis   = (float*)p; p += (size_t)NN * 4;
    float* stats = (float*)p; p += 1024 * 4;     // [0:2D) sums; c1 at +512, c2 at +640
    float* pool  = (float*)p; p += (size_t)BB * 256 * 4;
    float* part  = (float*)p; p += (size_t)BB * PSEG * 256 * 4;
    int* deg_i   = (int*)p; p += (size_t)NN * 4;
    int* rowptr  = (int*)p; p += (size_t)(NN + 1) * 4;
    int* cursor  = (int*)p; p += (size_t)NN * 4;
    int* bsum    = (int*)p; p += 256 * 4;
    int* boff    = (int*)p; p += 256 * 4;
    int* csr_src = (int*)p; p += (size_t)EE * 4;
    int* start   = (int*)p; p += (BB + 1) * 4;
    float* c1 = stats + 512;
    float* c2 = stats + 640;

    const int nb = (NN + 255) / 256;

    // weight plane split (tiny)
    cvt_wt_planes<<<(768 * 512 + 255) / 256, 256, 0, stream>>>(W[0], Wh[0], Wl[0], 768, 512);
    cvt_wt_planes<<<(512 * 256 + 255) / 256, 256, 0, stream>>>(W[1], Wh[1], Wl[1], 512, 256);
    cvt_wt_planes<<<(256 * 128 + 255) / 256, 256, 0, stream>>>(W[2], Wh[2], Wl[2], 256, 128);

    // degree + dis + CSR
    fill_i32<<<nb, 256, 0, stream>>>(deg_i, NN, 0);
    deg_edges<<<(EE + 255) / 256, 256, 0, stream>>>(ei, deg_i);
    scan_block<<<nb, 256, 0, stream>>>(deg_i, rowptr, bsum, dis);
    scan_sums<<<1, 256, 0, stream>>>(bsum, boff, nb);
    scan_fixup<<<nb, 256, 0, stream>>>(rowptr, boff, cursor);
    fill_csr<<<(EE + 255) / 256, 256, 0, stream>>>(ei, cursor, csr_src);

    const int dims[4] = {768, 512, 256, 128};

    for (int l = 0; l < 3; ++l) {
        int K = dims[l], D = dims[l + 1];

        dim3 gg(D / 128, MP / 128);
        if (l == 0)
            gemm_split3<0><<<gg, 256, 0, stream>>>((const unsigned int*)x, Wh[0], Wl[0],
                                                   hw, dis, K, D);
        else
            gemm_split3<1><<<gg, 256, 0, stream>>>(agg, Wh[l], Wl[l], hw, dis, K, D);

        int tpn = D / 8;
        int npb = 256 / tpn;
        agg_gather<<<(NN + npb - 1) / npb, 256, 0, stream>>>(hw, (float*)agg, rowptr, csr_src,
                                                             dis, bbv[l], D);

        fill_f32<<<(2 * D + 255) / 256, 256, 0, stream>>>(stats, 2 * D, 0.0f);
        bn_stats<<<dim3((D + 255) / 256, 256), 256, 0, stream>>>((const float*)agg, stats, D);
        if (l < 2) {
            size_t tot = (size_t)NN * D;
            bn_apply<<<(int)((tot + 255) / 256), 256, 0, stream>>>(agg, stats, gm[l], bt[l], D);
        } else {
            bn_coef<<<1, 128, 0, stream>>>(stats, gm[2], bt[2], c1, c2, 128);
        }
    }

    find_starts<<<nb, 256, 0, stream>>>(batch, start);
    dim3 pg(BB, PSEG);
    pool_part<<<pg, 128, 0, stream>>>((const float*)agg, start, c1, c2, part);
    pool_reduce<<<BB, 128, 0, stream>>>(part, start, pool);
    classifier_kernel<<<1, 256, 0, stream>>>(pool, Wc1, bc1, gc, bec, Wc2, bc2, out);
}

// Round 12
// 794.977 us; speedup vs baseline: 1.6054x; 1.0163x over previous
//
#include <hip/hip_runtime.h>
#include <cstddef>

#define NN 50000
#define EE 400000
#define BB 64
#define MP 50048            // padded rows: 391 * 128
#define BN_EPS 1e-5f
#define PSEG 32             // pooling segments per graph

typedef __attribute__((ext_vector_type(8))) short s16x8;
typedef __attribute__((ext_vector_type(4))) float f32x4;
typedef __attribute__((ext_vector_type(8))) _Float16 f16x8;

#define GLOAD_LDS16(g, l) __builtin_amdgcn_global_load_lds( \
    (const __attribute__((address_space(1))) void*)(g),     \
    (__attribute__((address_space(3))) void*)(l), 16, 0, 0)

// ---------------- utility ----------------
__global__ void fill_f32(float* __restrict__ p, int n, float v) {
    int i = blockIdx.x * blockDim.x + threadIdx.x;
    if (i < n) p[i] = v;
}

__global__ void fill_i32(int* __restrict__ p, int n, int v) {
    int i = blockIdx.x * blockDim.x + threadIdx.x;
    if (i < n) p[i] = v;
}

__global__ void deg_edges(const int* __restrict__ ei, int* __restrict__ deg) {
    int e = blockIdx.x * blockDim.x + threadIdx.x;
    if (e < EE) atomicAdd(&deg[ei[EE + e]], 1);
}

// W [K][N] fp32 -> two bf16 planes Wh/Wl [N][K] (hi = truncate, lo = residual)
__global__ void cvt_wt_planes(const float* __restrict__ W,
                              unsigned short* __restrict__ Wh,
                              unsigned short* __restrict__ Wl,
                              int K, int N) {
    int i = blockIdx.x * blockDim.x + threadIdx.x;
    if (i >= K * N) return;
    int k = i / N, n = i % N;
    float f = W[i];
    unsigned int fb = __float_as_uint(f);
    unsigned int hif = fb & 0xFFFF0000u;
    float lo = f - __uint_as_float(hif);
    Wh[(size_t)n * K + k] = (unsigned short)(hif >> 16);
    Wl[(size_t)n * K + k] = (unsigned short)(__float_as_uint(lo) >> 16);
}

// ---------------- CSR build (scan; rsqrt fused) ----------------
__global__ __launch_bounds__(256) void scan_block(const int* __restrict__ deg,
                                                  int* __restrict__ rowptr,
                                                  int* __restrict__ bsum,
                                                  float* __restrict__ dis) {
    __shared__ int tmp[256];
    int tid = threadIdx.x;
    int i = blockIdx.x * 256 + tid;
    int v = (i < NN) ? deg[i] : 0;
    if (i < NN) dis[i] = rsqrtf((float)v + 1.0f);
    tmp[tid] = v;
    __syncthreads();
#pragma unroll
    for (int off = 1; off < 256; off <<= 1) {
        int t = (tid >= off) ? tmp[tid - off] : 0;
        __syncthreads();
        tmp[tid] += t;
        __syncthreads();
    }
    if (i < NN) rowptr[i] = tmp[tid] - v;
    if (tid == 255) bsum[blockIdx.x] = tmp[255];
}

__global__ __launch_bounds__(256) void scan_sums(const int* __restrict__ bsum,
                                                 int* __restrict__ boff, int nb) {
    __shared__ int tmp[256];
    int tid = threadIdx.x;
    int v = (tid < nb) ? bsum[tid] : 0;
    tmp[tid] = v;
    __syncthreads();
#pragma unroll
    for (int off = 1; off < 256; off <<= 1) {
        int t = (tid >= off) ? tmp[tid - off] : 0;
        __syncthreads();
        tmp[tid] += t;
        __syncthreads();
    }
    boff[tid] = tmp[tid] - v;
}

__global__ void scan_fixup(int* __restrict__ rowptr, const int* __restrict__ boff,
                           int* __restrict__ cursor) {
    int i = blockIdx.x * blockDim.x + threadIdx.x;
    if (i < NN) {
        int v = rowptr[i] + boff[i >> 8];
        rowptr[i] = v;
        cursor[i] = v;
    }
    if (i == 0) rowptr[NN] = EE;
}

__global__ void fill_csr(const int* __restrict__ ei, int* __restrict__ cursor,
                         int* __restrict__ csr_src) {
    int e = blockIdx.x * blockDim.x + threadIdx.x;
    if (e >= EE) return;
    int s = ei[e];
    int t = ei[EE + e];
    int pos = atomicAdd(&cursor[t], 1);
    csr_src[pos] = s;
}

// ---------------- split helpers (mask/shift only — hardware-validated r5-r11) ------
static __device__ __forceinline__ void unpack_pk(const uint4& u0, const uint4& u1,
                                                 s16x8& h, s16x8& l) {
    unsigned int p[8] = {u0.x, u0.y, u0.z, u0.w, u1.x, u1.y, u1.z, u1.w};
    union { s16x8 v; unsigned int u[4]; } H, L;
#pragma unroll
    for (int k = 0; k < 4; ++k) {
        H.u[k] = (p[2 * k + 1] & 0xFFFF0000u) | (p[2 * k] >> 16);
        L.u[k] = (p[2 * k + 1] << 16) | (p[2 * k] & 0xFFFFu);
    }
    h = H.v; l = L.v;
}

static __device__ __forceinline__ void unpack_f32(const uint4& u0, const uint4& u1,
                                                  s16x8& h, s16x8& l) {
    unsigned int e[8] = {u0.x, u0.y, u0.z, u0.w, u1.x, u1.y, u1.z, u1.w};
    unsigned int hi[8], lo[8];
#pragma unroll
    for (int j = 0; j < 8; ++j) {
        hi[j] = e[j] & 0xFFFF0000u;
        float lf = __uint_as_float(e[j]) - __uint_as_float(hi[j]);
        lo[j] = __float_as_uint(lf);
    }
    union { s16x8 v; unsigned int u[4]; } H, L;
#pragma unroll
    for (int k = 0; k < 4; ++k) {
        H.u[k] = (hi[2 * k + 1]) | (hi[2 * k] >> 16);
        L.u[k] = (lo[2 * k + 1] & 0xFFFF0000u) | (lo[2 * k] >> 16);
    }
    h = H.v; l = L.v;
}

// ------ split-bf16 3-MFMA GEMM, double-buffered, XCD-swizzled 1D grid ------
// C[MP,N] = dis[row] * (A[MP,K] @ W[N,K]^T), fp16 out. B pre-split bf16 planes.
// AMODE 0: A fp32 (in-kernel split). AMODE 1: A packed u32.
// Bijective XCD swizzle (m204): each XCD owns a contiguous row-major tile span,
// so the N/128 column-tiles sharing an A-panel co-locate on one XCD's L2.
template <int AMODE>
__global__ __launch_bounds__(256) void gemm_split3(const unsigned int* __restrict__ A,
                                                   const unsigned short* __restrict__ Bh,
                                                   const unsigned short* __restrict__ Bl,
                                                   _Float16* __restrict__ C,
                                                   const float* __restrict__ dis,
                                                   int K, int N) {
    __shared__ unsigned int As[2][128 * 32];     // 2 x 16 KB
    __shared__ unsigned short Bsh[2][128 * 32];  // 2 x 8 KB
    __shared__ unsigned short Bsl[2][128 * 32];  // 2 x 8 KB  (total 64 KB)
    const int tid = threadIdx.x;
    const int w  = tid >> 6;
    const int lw = tid & 63;
    const int lo = lw & 15;
    const int hi = lw >> 4;
    const int wr = w >> 1, wc = w & 1;

    // XCD-aware bijective remap (guide m204): orig%8 = XCD under round-robin dispatch
    const int nwg = gridDim.x;
    const int q = nwg >> 3, r = nwg & 7;
    {
    }
    int orig = blockIdx.x;
    int xcd = orig & 7, idx = orig >> 3;
    int lid = (xcd < r) ? (xcd * (q + 1) + idx) : (r * (q + 1) + (xcd - r) * q + idx);
    const int nbx = N >> 7;                     // 4 / 2 / 1 (power of 2)
    const int lbx = (nbx == 4) ? 2 : (nbx == 2 ? 1 : 0);
    const int rowBase = (lid >> lbx) * 128;
    const int colBase = (lid & (nbx - 1)) * 128;

    const int arow = w * 8 + (lw >> 3);
    const int acol = (lw & 7) * 4;
    const int brow = w * 16 + (lw >> 2);
    const int bcol = (lw & 3) * 8;

    f32x4 acc[4][4];
#pragma unroll
    for (int m = 0; m < 4; ++m)
#pragma unroll
        for (int n = 0; n < 4; ++n) acc[m][n] = (f32x4){0.f, 0.f, 0.f, 0.f};

#define STAGE(buf, k0s) do {                                                        \
    _Pragma("unroll")                                                               \
    for (int i_ = 0; i_ < 4; ++i_) {                                                \
        int gr_ = rowBase + i_ * 32 + arow;                                         \
        gr_ = (gr_ < NN) ? gr_ : (NN - 1);                                          \
        GLOAD_LDS16(A + (size_t)gr_ * K + (k0s) + acol,                             \
                    (char*)&As[buf][0] + i_ * 4096 + w * 1024);                     \
    }                                                                               \
    _Pragma("unroll")                                                               \
    for (int j_ = 0; j_ < 2; ++j_) {                                                \
        int gc_ = colBase + j_ * 64 + brow;                                         \
        GLOAD_LDS16(Bh + (size_t)gc_ * K + (k0s) + bcol,                            \
                    (char*)&Bsh[buf][0] + j_ * 4096 + w * 1024);                    \
        GLOAD_LDS16(Bl + (size_t)gc_ * K + (k0s) + bcol,                            \
                    (char*)&Bsl[buf][0] + j_ * 4096 + w * 1024);                    \
    }                                                                               \
} while (0)

    STAGE(0, 0);
    asm volatile("s_waitcnt vmcnt(0)" ::: "memory");
    __builtin_amdgcn_s_barrier();

    const int nt = K >> 5;
    int cur = 0;
    for (int t = 0; t < nt; ++t) {
        if (t + 1 < nt) STAGE(cur ^ 1, (t + 1) << 5);   // prefetch next tile (async)

        s16x8 ah[4], al[4], bh[4], bl[4];
#pragma unroll
        for (int m = 0; m < 4; ++m) {
            int rr = wr * 64 + m * 16 + lo;
            uint4 u0 = *(const uint4*)&As[cur][rr * 32 + hi * 8];
            uint4 u1 = *(const uint4*)&As[cur][rr * 32 + hi * 8 + 4];
            if (AMODE == 0) unpack_f32(u0, u1, ah[m], al[m]);
            else            unpack_pk(u0, u1, ah[m], al[m]);
        }
#pragma unroll
        for (int n = 0; n < 4; ++n) {
            int rr = wc * 64 + n * 16 + lo;
            bh[n] = *(const s16x8*)&Bsh[cur][rr * 32 + hi * 8];
            bl[n] = *(const s16x8*)&Bsl[cur][rr * 32 + hi * 8];
        }
#pragma unroll
        for (int m = 0; m < 4; ++m)
#pragma unroll
            for (int n = 0; n < 4; ++n) {
                acc[m][n] = __builtin_amdgcn_mfma_f32_16x16x32_bf16(ah[m], bh[n], acc[m][n], 0, 0, 0);
                acc[m][n] = __builtin_amdgcn_mfma_f32_16x16x32_bf16(ah[m], bl[n], acc[m][n], 0, 0, 0);
                acc[m][n] = __builtin_amdgcn_mfma_f32_16x16x32_bf16(al[m], bh[n], acc[m][n], 0, 0, 0);
            }

        asm volatile("s_waitcnt vmcnt(0)" ::: "memory");
        __builtin_amdgcn_s_barrier();
        cur ^= 1;
    }
#undef STAGE

#pragma unroll
    for (int m = 0; m < 4; ++m) {
        int row0 = rowBase + wr * 64 + m * 16 + hi * 4;
#pragma unroll
        for (int j = 0; j < 4; ++j) {
            int rr = row0 + j;
            float ds = dis[(rr < NN) ? rr : (NN - 1)];
#pragma unroll
            for (int n = 0; n < 4; ++n) {
                int col = colBase + wc * 64 + n * 16 + lo;
                C[(size_t)rr * N + col] = (_Float16)(ds * acc[m][n][j]);
            }
        }
    }
}

// ------ gather aggregation: fp16 hws in, fp32 agg out, 4-edge unroll (validated) ------
__global__ __launch_bounds__(256) void agg_gather(const _Float16* __restrict__ hws,
                                                  float* __restrict__ agg,
                                                  const int* __restrict__ rowptr,
                                                  const int* __restrict__ csr_src,
                                                  const float* __restrict__ dis,
                                                  const float* __restrict__ bias,
                                                  int D) {
    const int tpn = D >> 3;
    const int npb = 256 / tpn;
    const int local = threadIdx.x / tpn;
    const int lane = threadIdx.x % tpn;
    const int n = blockIdx.x * npb + local;
    if (n >= NN) return;
    const int dq = lane * 8;

    f16x8 sv = *(const f16x8*)&hws[(size_t)n * D + dq];
    float a[8];
#pragma unroll
    for (int j = 0; j < 8; ++j) a[j] = (float)sv[j];

    int e0 = rowptr[n], e1 = rowptr[n + 1];
    int e = e0;
    for (; e + 4 <= e1; e += 4) {
        int s0 = csr_src[e + 0];
        int s1 = csr_src[e + 1];
        int s2 = csr_src[e + 2];
        int s3 = csr_src[e + 3];
        f16x8 v0 = *(const f16x8*)&hws[(size_t)s0 * D + dq];
        f16x8 v1 = *(const f16x8*)&hws[(size_t)s1 * D + dq];
        f16x8 v2 = *(const f16x8*)&hws[(size_t)s2 * D + dq];
        f16x8 v3 = *(const f16x8*)&hws[(size_t)s3 * D + dq];
#pragma unroll
        for (int j = 0; j < 8; ++j)
            a[j] += ((float)v0[j] + (float)v1[j]) + ((float)v2[j] + (float)v3[j]);
    }
    for (; e < e1; ++e) {
        int s = csr_src[e];
        f16x8 v = *(const f16x8*)&hws[(size_t)s * D + dq];
#pragma unroll
        for (int j = 0; j < 8; ++j) a[j] += (float)v[j];
    }

    float din = dis[n];
    f32x4 o0, o1;
#pragma unroll
    for (int j = 0; j < 4; ++j) o0[j] = din * a[j] + bias[dq + j];
#pragma unroll
    for (int j = 0; j < 4; ++j) o1[j] = din * a[4 + j] + bias[dq + 4 + j];
    *(f32x4*)&agg[(size_t)n * D + dq] = o0;
    *(f32x4*)&agg[(size_t)n * D + dq + 4] = o1;
}

// ---------------- batchnorm stats (column-striped, validated) ----------------
__global__ void bn_stats(const float* __restrict__ h, float* __restrict__ stats, int D) {
    int d = blockIdx.x * blockDim.x + threadIdx.x;
    if (d >= D) return;
    float s = 0.f, ss = 0.f;
    for (int n = blockIdx.y; n < NN; n += gridDim.y) {
        float v = h[(size_t)n * D + d];
        s += v;
        ss += v * v;
    }
    atomicAdd(&stats[d], s);
    atomicAdd(&stats[D + d], ss);
}

// ---------------- batchnorm apply (relu + split-pack in place; layers 0,1) -------
__global__ void bn_apply(unsigned int* __restrict__ buf,
                         const float* __restrict__ stats,
                         const float* __restrict__ gamma, const float* __restrict__ beta,
                         int D) {
    size_t i = (size_t)blockIdx.x * blockDim.x + threadIdx.x;
    if (i >= (size_t)NN * D) return;
    int d = (int)(i % (size_t)D);
    float mean = stats[d] * (1.0f / NN);
    float var  = stats[D + d] * (1.0f / NN) - mean * mean;
    float f = (__uint_as_float(buf[i]) - mean) * rsqrtf(var + BN_EPS) * gamma[d] + beta[d];
    f = fmaxf(f, 0.f);
    unsigned int fb = __float_as_uint(f);
    unsigned int hif = fb & 0xFFFF0000u;
    float lf = f - __uint_as_float(hif);
    buf[i] = hif | (__float_as_uint(lf) >> 16);
}

// ---------------- layer-2 BN coefficients ----------------
__global__ void bn_coef(const float* __restrict__ stats,
                        const float* __restrict__ gamma, const float* __restrict__ beta,
                        float* __restrict__ c1, float* __restrict__ c2, int D) {
    int d = blockIdx.x * blockDim.x + threadIdx.x;
    if (d >= D) return;
    float mean = stats[d] * (1.0f / NN);
    float var  = stats[D + d] * (1.0f / NN) - mean * mean;
    float r = rsqrtf(var + BN_EPS) * gamma[d];
    c1[d] = r;
    c2[d] = beta[d] - mean * r;
}

// ---------------- pooling (two-stage segmented, BN affine fused; validated) ------
__global__ void find_starts(const int* __restrict__ batch, int* __restrict__ start) {
    int n = blockIdx.x * blockDim.x + threadIdx.x;
    if (n >= NN) return;
    int bc = batch[n];
    int bp = (n == 0) ? -1 : batch[n - 1];
    for (int g = bp + 1; g <= bc; ++g) start[g] = n;
    if (n == NN - 1) {
        for (int g = bc + 1; g <= BB; ++g) start[g] = NN;
    }
}

__global__ void pool_part(const float* __restrict__ h, const int* __restrict__ start,
                          const float* __restrict__ c1, const float* __restrict__ c2,
                          float* __restrict__ part) {
    int b = blockIdx.x;
    int seg = blockIdx.y;
    int d = threadIdx.x;
    int s0 = start[b], s1 = start[b + 1];
    int len = s1 - s0;
    int a = s0 + (int)((long long)len * seg / PSEG);
    int e = s0 + (int)((long long)len * (seg + 1) / PSEG);
    float a1 = c1[d], a2 = c2[d];
    float sum = 0.f;
    float mx = -3.402823466e+38f;
    for (int n = a; n < e; ++n) {
        float v = a1 * h[(size_t)n * 128 + d] + a2;
        sum += v;
        mx = fmaxf(mx, v);
    }
    part[(size_t)(b * PSEG + seg) * 256 + d] = sum;
    part[(size_t)(b * PSEG + seg) * 256 + 128 + d] = mx;
}

__global__ void pool_reduce(const float* __restrict__ part, const int* __restrict__ start,
                            float* __restrict__ pool) {
    int b = blockIdx.x;
    int d = threadIdx.x;
    float sum = 0.f;
    float mx = -3.402823466e+38f;
    for (int s = 0; s < PSEG; ++s) {
        sum += part[(size_t)(b * PSEG + s) * 256 + d];
        mx = fmaxf(mx, part[(size_t)(b * PSEG + s) * 256 + 128 + d]);
    }
    float cnt = fmaxf((float)(start[b + 1] - start[b]), 1.0f);
    pool[b * 256 + d] = sum / cnt;
    pool[b * 256 + 128 + d] = mx;
}

// ---------------- classifier (single block, fp32) ----------------
__global__ __launch_bounds__(256) void classifier_kernel(
        const float* __restrict__ pool,
        const float* __restrict__ Wc1, const float* __restrict__ bc1,
        const float* __restrict__ gc, const float* __restrict__ bec,
        const float* __restrict__ Wc2, const float* __restrict__ bc2,
        float* __restrict__ out) {
    __shared__ float hc[64][65];
    __shared__ float cmean[64];
    __shared__ float crstd[64];
    int tid = threadIdx.x;

    for (int i = tid; i < 64 * 64; i += 256) {
        int r = i / 64, c = i % 64;
        float acc = bc1[c];
        for (int k = 0; k < 256; ++k)
            acc += pool[r * 256 + k] * Wc1[k * 64 + c];
        hc[r][c] = fmaxf(acc, 0.f);
    }
    __syncthreads();

    if (tid < 64) {
        float s = 0.f, ss = 0.f;
        for (int r = 0; r < 64; ++r) {
            float v = hc[r][tid];
            s += v;
            ss += v * v;
        }
        float m = s * (1.0f / 64.0f);
        float var = ss * (1.0f / 64.0f) - m * m;
        cmean[tid] = m;
        crstd[tid] = rsqrtf(var + BN_EPS);
    }
    __syncthreads();

    if (tid < 128) {
        int r = tid / 2, k = tid % 2;
        float acc = bc2[k];
        for (int c = 0; c < 64; ++c) {
            float v = (hc[r][c] - cmean[c]) * crstd[c] * gc[c] + bec[c];
            acc += v * Wc2[c * 2 + k];
        }
        out[r * 2 + k] = acc;
    }
}

// ---------------- launch ----------------
extern "C" void kernel_launch(void* const* d_in, const int* in_sizes, int n_in,
                              void* d_out, int out_size, void* d_ws, size_t ws_size,
                              hipStream_t stream) {
    const float* x     = (const float*)d_in[0];
    const int*   ei    = (const int*)d_in[1];
    const int*   batch = (const int*)d_in[2];
    const float* W[3]  = {(const float*)d_in[3], (const float*)d_in[7], (const float*)d_in[11]};
    const float* bbv[3] = {(const float*)d_in[4], (const float*)d_in[8], (const float*)d_in[12]};
    const float* gm[3] = {(const float*)d_in[5], (const float*)d_in[9], (const float*)d_in[13]};
    const float* bt[3] = {(const float*)d_in[6], (const float*)d_in[10], (const float*)d_in[14]};
    const float* Wc1 = (const float*)d_in[15];
    const float* bc1 = (const float*)d_in[16];
    const float* gc  = (const float*)d_in[17];
    const float* bec = (const float*)d_in[18];
    const float* Wc2 = (const float*)d_in[19];
    const float* bc2 = (const float*)d_in[20];
    float* out = (float*)d_out;

    // workspace carve-up (r11-identical)
    char* p = (char*)d_ws;
    _Float16* hw = (_Float16*)p; p += (size_t)MP * 512 * 2;           // fp16 dis-scaled GEMM out
    unsigned int* agg = (unsigned int*)p; p += (size_t)NN * 512 * 4;  // agg f32 / h packed
    unsigned short* Wh[3];
    unsigned short* Wl[3];
    Wh[0] = (unsigned short*)p; p += (size_t)512 * 768 * 2;
    Wl[0] = (unsigned short*)p; p += (size_t)512 * 768 * 2;
    Wh[1] = (unsigned short*)p; p += (size_t)256 * 512 * 2;
    Wl[1] = (unsigned short*)p; p += (size_t)256 * 512 * 2;
    Wh[2] = (unsigned short*)p; p += (size_t)128 * 256 * 2;
    Wl[2] = (unsigned short*)p; p += (size_t)128 * 256 * 2;
    float* dis   = (float*)p; p += (size_t)NN * 4;
    float* stats = (float*)p; p += 2048 * 4;     // [0:2D) sums; c1 at +1024, c2 at +1152
    float* pool  = (float*)p; p += (size_t)BB * 256 * 4;
    float* part  = (float*)p; p += (size_t)BB * PSEG * 256 * 4;
    int* deg_i   = (int*)p; p += (size_t)NN * 4;
    int* rowptr  = (int*)p; p += (size_t)(NN + 1) * 4;
    int* cursor  = (int*)p; p += (size_t)NN * 4;
    int* bsum    = (int*)p; p += 256 * 4;
    int* boff    = (int*)p; p += 256 * 4;
    int* csr_src = (int*)p; p += (size_t)EE * 4;
    int* start   = (int*)p; p += (BB + 1) * 4;
    float* c1 = stats + 1024;
    float* c2 = stats + 1152;

    const int nb = (NN + 255) / 256;

    // weight plane split (tiny)
    cvt_wt_planes<<<(768 * 512 + 255) / 256, 256, 0, stream>>>(W[0], Wh[0], Wl[0], 768, 512);
    cvt_wt_planes<<<(512 * 256 + 255) / 256, 256, 0, stream>>>(W[1], Wh[1], Wl[1], 512, 256);
    cvt_wt_planes<<<(256 * 128 + 255) / 256, 256, 0, stream>>>(W[2], Wh[2], Wl[2], 256, 128);

    // degree + dis + CSR
    fill_i32<<<nb, 256, 0, stream>>>(deg_i, NN, 0);
    deg_edges<<<(EE + 255) / 256, 256, 0, stream>>>(ei, deg_i);
    scan_block<<<nb, 256, 0, stream>>>(deg_i, rowptr, bsum, dis);
    scan_sums<<<1, 256, 0, stream>>>(bsum, boff, nb);
    scan_fixup<<<nb, 256, 0, stream>>>(rowptr, boff, cursor);
    fill_csr<<<(EE + 255) / 256, 256, 0, stream>>>(ei, cursor, csr_src);

    const int dims[4] = {768, 512, 256, 128};

    for (int l = 0; l < 3; ++l) {
        int K = dims[l], D = dims[l + 1];

        int nwg = (D / 128) * (MP / 128);
        if (l == 0)
            gemm_split3<0><<<nwg, 256, 0, stream>>>((const unsigned int*)x, Wh[0], Wl[0],
                                                    hw, dis, K, D);
        else
            gemm_split3<1><<<nwg, 256, 0, stream>>>(agg, Wh[l], Wl[l], hw, dis, K, D);

        int tpn = D / 8;
        int npb = 256 / tpn;
        agg_gather<<<(NN + npb - 1) / npb, 256, 0, stream>>>(hw, (float*)agg, rowptr, csr_src,
                                                             dis, bbv[l], D);

        fill_f32<<<(2 * D + 255) / 256, 256, 0, stream>>>(stats, 2 * D, 0.0f);
        bn_stats<<<dim3((D + 255) / 256, 256), 256, 0, stream>>>((const float*)agg, stats, D);
        if (l < 2) {
            size_t tot = (size_t)NN * D;
            bn_apply<<<(int)((tot + 255) / 256), 256, 0, stream>>>(agg, stats, gm[l], bt[l], D);
        } else {
            bn_coef<<<1, 128, 0, stream>>>(stats, gm[2], bt[2], c1, c2, 128);
        }
    }

    find_starts<<<nb, 256, 0, stream>>>(batch, start);
    dim3 pg(BB, PSEG);
    pool_part<<<pg, 128, 0, stream>>>((const float*)agg, start, c1, c2, part);
    pool_reduce<<<BB, 128, 0, stream>>>(part, start, pool);
    classifier_kernel<<<1, 256, 0, stream>>>(pool, Wc1, bc1, gc, bec, Wc2, bc2, out);
}

// Round 13
// 790.686 us; speedup vs baseline: 1.6141x; 1.0054x over previous
//
#include <hip/hip_runtime.h>
#include <cstddef>

#define NN 50000
#define EE 400000
#define BB 64
#define MP 50048            // padded rows: 391 * 128
#define BN_EPS 1e-5f
#define PSEG 32             // pooling segments per graph

typedef __attribute__((ext_vector_type(8))) short s16x8;
typedef __attribute__((ext_vector_type(4))) float f32x4;
typedef __attribute__((ext_vector_type(8))) _Float16 f16x8;

#define GLOAD_LDS16(g, l) __builtin_amdgcn_global_load_lds( \
    (const __attribute__((address_space(1))) void*)(g),     \
    (__attribute__((address_space(3))) void*)(l), 16, 0, 0)

// ---------------- utility ----------------
__global__ void fill_f32(float* __restrict__ p, int n, float v) {
    int i = blockIdx.x * blockDim.x + threadIdx.x;
    if (i < n) p[i] = v;
}

__global__ void fill_i32(int* __restrict__ p, int n, int v) {
    int i = blockIdx.x * blockDim.x + threadIdx.x;
    if (i < n) p[i] = v;
}

__global__ void deg_edges(const int* __restrict__ ei, int* __restrict__ deg) {
    int e = blockIdx.x * blockDim.x + threadIdx.x;
    if (e < EE) atomicAdd(&deg[ei[EE + e]], 1);
}

// W [K][N] fp32 -> two bf16 planes Wh/Wl [N][K] (hi = truncate, lo = residual)
__global__ void cvt_wt_planes(const float* __restrict__ W,
                              unsigned short* __restrict__ Wh,
                              unsigned short* __restrict__ Wl,
                              int K, int N) {
    int i = blockIdx.x * blockDim.x + threadIdx.x;
    if (i >= K * N) return;
    int k = i / N, n = i % N;
    float f = W[i];
    unsigned int fb = __float_as_uint(f);
    unsigned int hif = fb & 0xFFFF0000u;
    float lo = f - __uint_as_float(hif);
    Wh[(size_t)n * K + k] = (unsigned short)(hif >> 16);
    Wl[(size_t)n * K + k] = (unsigned short)(__float_as_uint(lo) >> 16);
}

// ---------------- CSR build (scan; rsqrt fused) ----------------
__global__ __launch_bounds__(256) void scan_block(const int* __restrict__ deg,
                                                  int* __restrict__ rowptr,
                                                  int* __restrict__ bsum,
                                                  float* __restrict__ dis) {
    __shared__ int tmp[256];
    int tid = threadIdx.x;
    int i = blockIdx.x * 256 + tid;
    int v = (i < NN) ? deg[i] : 0;
    if (i < NN) dis[i] = rsqrtf((float)v + 1.0f);
    tmp[tid] = v;
    __syncthreads();
#pragma unroll
    for (int off = 1; off < 256; off <<= 1) {
        int t = (tid >= off) ? tmp[tid - off] : 0;
        __syncthreads();
        tmp[tid] += t;
        __syncthreads();
    }
    if (i < NN) rowptr[i] = tmp[tid] - v;
    if (tid == 255) bsum[blockIdx.x] = tmp[255];
}

__global__ __launch_bounds__(256) void scan_sums(const int* __restrict__ bsum,
                                                 int* __restrict__ boff, int nb) {
    __shared__ int tmp[256];
    int tid = threadIdx.x;
    int v = (tid < nb) ? bsum[tid] : 0;
    tmp[tid] = v;
    __syncthreads();
#pragma unroll
    for (int off = 1; off < 256; off <<= 1) {
        int t = (tid >= off) ? tmp[tid - off] : 0;
        __syncthreads();
        tmp[tid] += t;
        __syncthreads();
    }
    boff[tid] = tmp[tid] - v;
}

__global__ void scan_fixup(int* __restrict__ rowptr, const int* __restrict__ boff,
                           int* __restrict__ cursor) {
    int i = blockIdx.x * blockDim.x + threadIdx.x;
    if (i < NN) {
        int v = rowptr[i] + boff[i >> 8];
        rowptr[i] = v;
        cursor[i] = v;
    }
    if (i == 0) rowptr[NN] = EE;
}

__global__ void fill_csr(const int* __restrict__ ei, int* __restrict__ cursor,
                         int* __restrict__ csr_src) {
    int e = blockIdx.x * blockDim.x + threadIdx.x;
    if (e >= EE) return;
    int s = ei[e];
    int t = ei[EE + e];
    int pos = atomicAdd(&cursor[t], 1);
    csr_src[pos] = s;
}

// ---------------- split helpers (mask/shift only — hardware-validated r5-r12) ------
static __device__ __forceinline__ void unpack_pk(const uint4& u0, const uint4& u1,
                                                 s16x8& h, s16x8& l) {
    unsigned int p[8] = {u0.x, u0.y, u0.z, u0.w, u1.x, u1.y, u1.z, u1.w};
    union { s16x8 v; unsigned int u[4]; } H, L;
#pragma unroll
    for (int k = 0; k < 4; ++k) {
        H.u[k] = (p[2 * k + 1] & 0xFFFF0000u) | (p[2 * k] >> 16);
        L.u[k] = (p[2 * k + 1] << 16) | (p[2 * k] & 0xFFFFu);
    }
    h = H.v; l = L.v;
}

static __device__ __forceinline__ void unpack_f32(const uint4& u0, const uint4& u1,
                                                  s16x8& h, s16x8& l) {
    unsigned int e[8] = {u0.x, u0.y, u0.z, u0.w, u1.x, u1.y, u1.z, u1.w};
    unsigned int hi[8], lo[8];
#pragma unroll
    for (int j = 0; j < 8; ++j) {
        hi[j] = e[j] & 0xFFFF0000u;
        float lf = __uint_as_float(e[j]) - __uint_as_float(hi[j]);
        lo[j] = __float_as_uint(lf);
    }
    union { s16x8 v; unsigned int u[4]; } H, L;
#pragma unroll
    for (int k = 0; k < 4; ++k) {
        H.u[k] = (hi[2 * k + 1]) | (hi[2 * k] >> 16);
        L.u[k] = (lo[2 * k + 1] & 0xFFFF0000u) | (lo[2 * k] >> 16);
    }
    h = H.v; l = L.v;
}

// ------ split-bf16 3-MFMA GEMM, dbuf + XCD swizzle + T2 LDS chunk-XOR-swizzle ------
// C[MP,N] = dis[row] * (A[MP,K] @ W[N,K]^T), fp16 out. B pre-split bf16 planes.
// LDS swizzle (both-sides, rule #21): global 16B chunk g of row r stored at LDS
// chunk position g^(r&7) for A (g^(r&3) for B) via pre-swizzled GLOBAL source;
// read applies the same XOR. A-reads 16-way -> 2-way, B-reads 8-way -> 4-way.
template <int AMODE>
__global__ __launch_bounds__(256) void gemm_split3(const unsigned int* __restrict__ A,
                                                   const unsigned short* __restrict__ Bh,
                                                   const unsigned short* __restrict__ Bl,
                                                   _Float16* __restrict__ C,
                                                   const float* __restrict__ dis,
                                                   int K, int N) {
    __shared__ unsigned int As[2][128 * 32];     // 2 x 16 KB
    __shared__ unsigned short Bsh[2][128 * 32];  // 2 x 8 KB
    __shared__ unsigned short Bsl[2][128 * 32];  // 2 x 8 KB  (total 64 KB)
    const int tid = threadIdx.x;
    const int w  = tid >> 6;
    const int lw = tid & 63;
    const int lo = lw & 15;
    const int hi = lw >> 4;
    const int wr = w >> 1, wc = w & 1;

    // XCD-aware bijective remap (m204)
    const int nwg = gridDim.x;
    const int q = nwg >> 3, r = nwg & 7;
    int orig = blockIdx.x;
    int xcd = orig & 7, idx = orig >> 3;
    int lid = (xcd < r) ? (xcd * (q + 1) + idx) : (r * (q + 1) + (xcd - r) * q + idx);
    const int nbx = N >> 7;
    const int lbx = (nbx == 4) ? 2 : (nbx == 2 ? 1 : 0);
    const int rowBase = (lid >> lbx) * 128;
    const int colBase = (lid & (nbx - 1)) * 128;

    const int arow = w * 8 + (lw >> 3);
    const int acol = ((lw & 7) ^ (lw >> 3)) * 4;           // pre-swizzled A source chunk
    const int brow = w * 16 + (lw >> 2);
    const int bcol = ((lw & 3) ^ ((lw >> 2) & 3)) * 8;     // pre-swizzled B source chunk

    f32x4 acc[4][4];
#pragma unroll
    for (int m = 0; m < 4; ++m)
#pragma unroll
        for (int n = 0; n < 4; ++n) acc[m][n] = (f32x4){0.f, 0.f, 0.f, 0.f};

#define STAGE(buf, k0s) do {                                                        \
    _Pragma("unroll")                                                               \
    for (int i_ = 0; i_ < 4; ++i_) {                                                \
        int gr_ = rowBase + i_ * 32 + arow;                                         \
        gr_ = (gr_ < NN) ? gr_ : (NN - 1);                                          \
        GLOAD_LDS16(A + (size_t)gr_ * K + (k0s) + acol,                             \
                    (char*)&As[buf][0] + i_ * 4096 + w * 1024);                     \
    }                                                                               \
    _Pragma("unroll")                                                               \
    for (int j_ = 0; j_ < 2; ++j_) {                                                \
        int gc_ = colBase + j_ * 64 + brow;                                         \
        GLOAD_LDS16(Bh + (size_t)gc_ * K + (k0s) + bcol,                            \
                    (char*)&Bsh[buf][0] + j_ * 4096 + w * 1024);                    \
        GLOAD_LDS16(Bl + (size_t)gc_ * K + (k0s) + bcol,                            \
                    (char*)&Bsl[buf][0] + j_ * 4096 + w * 1024);                    \
    }                                                                               \
} while (0)

    STAGE(0, 0);
    asm volatile("s_waitcnt vmcnt(0)" ::: "memory");
    __builtin_amdgcn_s_barrier();

    const int nt = K >> 5;
    int cur = 0;
    for (int t = 0; t < nt; ++t) {
        if (t + 1 < nt) STAGE(cur ^ 1, (t + 1) << 5);

        s16x8 ah[4], al[4], bh[4], bl[4];
#pragma unroll
        for (int m = 0; m < 4; ++m) {
            int rr = wr * 64 + m * 16 + lo;
            int c0 = ((hi * 2) ^ (rr & 7)) * 4;
            int c1 = ((hi * 2 + 1) ^ (rr & 7)) * 4;
            uint4 u0 = *(const uint4*)&As[cur][rr * 32 + c0];
            uint4 u1 = *(const uint4*)&As[cur][rr * 32 + c1];
            if (AMODE == 0) unpack_f32(u0, u1, ah[m], al[m]);
            else            unpack_pk(u0, u1, ah[m], al[m]);
        }
#pragma unroll
        for (int n = 0; n < 4; ++n) {
            int rr = wc * 64 + n * 16 + lo;
            int cb = (hi ^ (rr & 3)) * 8;
            bh[n] = *(const s16x8*)&Bsh[cur][rr * 32 + cb];
            bl[n] = *(const s16x8*)&Bsl[cur][rr * 32 + cb];
        }
#pragma unroll
        for (int m = 0; m < 4; ++m)
#pragma unroll
            for (int n = 0; n < 4; ++n) {
                acc[m][n] = __builtin_amdgcn_mfma_f32_16x16x32_bf16(ah[m], bh[n], acc[m][n], 0, 0, 0);
                acc[m][n] = __builtin_amdgcn_mfma_f32_16x16x32_bf16(ah[m], bl[n], acc[m][n], 0, 0, 0);
                acc[m][n] = __builtin_amdgcn_mfma_f32_16x16x32_bf16(al[m], bh[n], acc[m][n], 0, 0, 0);
            }

        asm volatile("s_waitcnt vmcnt(0)" ::: "memory");
        __builtin_amdgcn_s_barrier();
        cur ^= 1;
    }
#undef STAGE

#pragma unroll
    for (int m = 0; m < 4; ++m) {
        int row0 = rowBase + wr * 64 + m * 16 + hi * 4;
#pragma unroll
        for (int j = 0; j < 4; ++j) {
            int rr = row0 + j;
            float ds = dis[(rr < NN) ? rr : (NN - 1)];
#pragma unroll
            for (int n = 0; n < 4; ++n) {
                int col = colBase + wc * 64 + n * 16 + lo;
                C[(size_t)rr * N + col] = (_Float16)(ds * acc[m][n][j]);
            }
        }
    }
}

// ------ gather aggregation: fp16 hws in, fp32 agg out, 4-edge unroll (validated) ------
__global__ __launch_bounds__(256) void agg_gather(const _Float16* __restrict__ hws,
                                                  float* __restrict__ agg,
                                                  const int* __restrict__ rowptr,
                                                  const int* __restrict__ csr_src,
                                                  const float* __restrict__ dis,
                                                  const float* __restrict__ bias,
                                                  int D) {
    const int tpn = D >> 3;
    const int npb = 256 / tpn;
    const int local = threadIdx.x / tpn;
    const int lane = threadIdx.x % tpn;
    const int n = blockIdx.x * npb + local;
    if (n >= NN) return;
    const int dq = lane * 8;

    f16x8 sv = *(const f16x8*)&hws[(size_t)n * D + dq];
    float a[8];
#pragma unroll
    for (int j = 0; j < 8; ++j) a[j] = (float)sv[j];

    int e0 = rowptr[n], e1 = rowptr[n + 1];
    int e = e0;
    for (; e + 4 <= e1; e += 4) {
        int s0 = csr_src[e + 0];
        int s1 = csr_src[e + 1];
        int s2 = csr_src[e + 2];
        int s3 = csr_src[e + 3];
        f16x8 v0 = *(const f16x8*)&hws[(size_t)s0 * D + dq];
        f16x8 v1 = *(const f16x8*)&hws[(size_t)s1 * D + dq];
        f16x8 v2 = *(const f16x8*)&hws[(size_t)s2 * D + dq];
        f16x8 v3 = *(const f16x8*)&hws[(size_t)s3 * D + dq];
#pragma unroll
        for (int j = 0; j < 8; ++j)
            a[j] += ((float)v0[j] + (float)v1[j]) + ((float)v2[j] + (float)v3[j]);
    }
    for (; e < e1; ++e) {
        int s = csr_src[e];
        f16x8 v = *(const f16x8*)&hws[(size_t)s * D + dq];
#pragma unroll
        for (int j = 0; j < 8; ++j) a[j] += (float)v[j];
    }

    float din = dis[n];
    f32x4 o0, o1;
#pragma unroll
    for (int j = 0; j < 4; ++j) o0[j] = din * a[j] + bias[dq + j];
#pragma unroll
    for (int j = 0; j < 4; ++j) o1[j] = din * a[4 + j] + bias[dq + 4 + j];
    *(f32x4*)&agg[(size_t)n * D + dq] = o0;
    *(f32x4*)&agg[(size_t)n * D + dq + 4] = o1;
}

// ---------------- batchnorm stats (column-striped, validated) ----------------
__global__ void bn_stats(const float* __restrict__ h, float* __restrict__ stats, int D) {
    int d = blockIdx.x * blockDim.x + threadIdx.x;
    if (d >= D) return;
    float s = 0.f, ss = 0.f;
    for (int n = blockIdx.y; n < NN; n += gridDim.y) {
        float v = h[(size_t)n * D + d];
        s += v;
        ss += v * v;
    }
    atomicAdd(&stats[d], s);
    atomicAdd(&stats[D + d], ss);
}

// ---------------- batchnorm apply (relu + split-pack in place; layers 0,1) -------
__global__ void bn_apply(unsigned int* __restrict__ buf,
                         const float* __restrict__ stats,
                         const float* __restrict__ gamma, const float* __restrict__ beta,
                         int D) {
    size_t i = (size_t)blockIdx.x * blockDim.x + threadIdx.x;
    if (i >= (size_t)NN * D) return;
    int d = (int)(i % (size_t)D);
    float mean = stats[d] * (1.0f / NN);
    float var  = stats[D + d] * (1.0f / NN) - mean * mean;
    float f = (__uint_as_float(buf[i]) - mean) * rsqrtf(var + BN_EPS) * gamma[d] + beta[d];
    f = fmaxf(f, 0.f);
    unsigned int fb = __float_as_uint(f);
    unsigned int hif = fb & 0xFFFF0000u;
    float lf = f - __uint_as_float(hif);
    buf[i] = hif | (__float_as_uint(lf) >> 16);
}

// ---------------- layer-2 BN coefficients ----------------
__global__ void bn_coef(const float* __restrict__ stats,
                        const float* __restrict__ gamma, const float* __restrict__ beta,
                        float* __restrict__ c1, float* __restrict__ c2, int D) {
    int d = blockIdx.x * blockDim.x + threadIdx.x;
    if (d >= D) return;
    float mean = stats[d] * (1.0f / NN);
    float var  = stats[D + d] * (1.0f / NN) - mean * mean;
    float r = rsqrtf(var + BN_EPS) * gamma[d];
    c1[d] = r;
    c2[d] = beta[d] - mean * r;
}

// ---------------- pooling (two-stage segmented, BN affine fused; validated) ------
__global__ void find_starts(const int* __restrict__ batch, int* __restrict__ start) {
    int n = blockIdx.x * blockDim.x + threadIdx.x;
    if (n >= NN) return;
    int bc = batch[n];
    int bp = (n == 0) ? -1 : batch[n - 1];
    for (int g = bp + 1; g <= bc; ++g) start[g] = n;
    if (n == NN - 1) {
        for (int g = bc + 1; g <= BB; ++g) start[g] = NN;
    }
}

__global__ void pool_part(const float* __restrict__ h, const int* __restrict__ start,
                          const float* __restrict__ c1, const float* __restrict__ c2,
                          float* __restrict__ part) {
    int b = blockIdx.x;
    int seg = blockIdx.y;
    int d = threadIdx.x;
    int s0 = start[b], s1 = start[b + 1];
    int len = s1 - s0;
    int a = s0 + (int)((long long)len * seg / PSEG);
    int e = s0 + (int)((long long)len * (seg + 1) / PSEG);
    float a1 = c1[d], a2 = c2[d];
    float sum = 0.f;
    float mx = -3.402823466e+38f;
    for (int n = a; n < e; ++n) {
        float v = a1 * h[(size_t)n * 128 + d] + a2;
        sum += v;
        mx = fmaxf(mx, v);
    }
    part[(size_t)(b * PSEG + seg) * 256 + d] = sum;
    part[(size_t)(b * PSEG + seg) * 256 + 128 + d] = mx;
}

__global__ void pool_reduce(const float* __restrict__ part, const int* __restrict__ start,
                            float* __restrict__ pool) {
    int b = blockIdx.x;
    int d = threadIdx.x;
    float sum = 0.f;
    float mx = -3.402823466e+38f;
    for (int s = 0; s < PSEG; ++s) {
        sum += part[(size_t)(b * PSEG + s) * 256 + d];
        mx = fmaxf(mx, part[(size_t)(b * PSEG + s) * 256 + 128 + d]);
    }
    float cnt = fmaxf((float)(start[b + 1] - start[b]), 1.0f);
    pool[b * 256 + d] = sum / cnt;
    pool[b * 256 + 128 + d] = mx;
}

// ---------------- classifier (single block, fp32) ----------------
__global__ __launch_bounds__(256) void classifier_kernel(
        const float* __restrict__ pool,
        const float* __restrict__ Wc1, const float* __restrict__ bc1,
        const float* __restrict__ gc, const float* __restrict__ bec,
        const float* __restrict__ Wc2, const float* __restrict__ bc2,
        float* __restrict__ out) {
    __shared__ float hc[64][65];
    __shared__ float cmean[64];
    __shared__ float crstd[64];
    int tid = threadIdx.x;

    for (int i = tid; i < 64 * 64; i += 256) {
        int r = i / 64, c = i % 64;
        float acc = bc1[c];
        for (int k = 0; k < 256; ++k)
            acc += pool[r * 256 + k] * Wc1[k * 64 + c];
        hc[r][c] = fmaxf(acc, 0.f);
    }
    __syncthreads();

    if (tid < 64) {
        float s = 0.f, ss = 0.f;
        for (int r = 0; r < 64; ++r) {
            float v = hc[r][tid];
            s += v;
            ss += v * v;
        }
        float m = s * (1.0f / 64.0f);
        float var = ss * (1.0f / 64.0f) - m * m;
        cmean[tid] = m;
        crstd[tid] = rsqrtf(var + BN_EPS);
    }
    __syncthreads();

    if (tid < 128) {
        int r = tid / 2, k = tid % 2;
        float acc = bc2[k];
        for (int c = 0; c < 64; ++c) {
            float v = (hc[r][c] - cmean[c]) * crstd[c] * gc[c] + bec[c];
            acc += v * Wc2[c * 2 + k];
        }
        out[r * 2 + k] = acc;
    }
}

// ---------------- launch ----------------
extern "C" void kernel_launch(void* const* d_in, const int* in_sizes, int n_in,
                              void* d_out, int out_size, void* d_ws, size_t ws_size,
                              hipStream_t stream) {
    const float* x     = (const float*)d_in[0];
    const int*   ei    = (const int*)d_in[1];
    const int*   batch = (const int*)d_in[2];
    const float* W[3]  = {(const float*)d_in[3], (const float*)d_in[7], (const float*)d_in[11]};
    const float* bbv[3] = {(const float*)d_in[4], (const float*)d_in[8], (const float*)d_in[12]};
    const float* gm[3] = {(const float*)d_in[5], (const float*)d_in[9], (const float*)d_in[13]};
    const float* bt[3] = {(const float*)d_in[6], (const float*)d_in[10], (const float*)d_in[14]};
    const float* Wc1 = (const float*)d_in[15];
    const float* bc1 = (const float*)d_in[16];
    const float* gc  = (const float*)d_in[17];
    const float* bec = (const float*)d_in[18];
    const float* Wc2 = (const float*)d_in[19];
    const float* bc2 = (const float*)d_in[20];
    float* out = (float*)d_out;

    // workspace carve-up (r12-identical)
    char* p = (char*)d_ws;
    _Float16* hw = (_Float16*)p; p += (size_t)MP * 512 * 2;           // fp16 dis-scaled GEMM out
    unsigned int* agg = (unsigned int*)p; p += (size_t)NN * 512 * 4;  // agg f32 / h packed
    unsigned short* Wh[3];
    unsigned short* Wl[3];
    Wh[0] = (unsigned short*)p; p += (size_t)512 * 768 * 2;
    Wl[0] = (unsigned short*)p; p += (size_t)512 * 768 * 2;
    Wh[1] = (unsigned short*)p; p += (size_t)256 * 512 * 2;
    Wl[1] = (unsigned short*)p; p += (size_t)256 * 512 * 2;
    Wh[2] = (unsigned short*)p; p += (size_t)128 * 256 * 2;
    Wl[2] = (unsigned short*)p; p += (size_t)128 * 256 * 2;
    float* dis   = (float*)p; p += (size_t)NN * 4;
    float* stats = (float*)p; p += 2048 * 4;
    float* pool  = (float*)p; p += (size_t)BB * 256 * 4;
    float* part  = (float*)p; p += (size_t)BB * PSEG * 256 * 4;
    int* deg_i   = (int*)p; p += (size_t)NN * 4;
    int* rowptr  = (int*)p; p += (size_t)(NN + 1) * 4;
    int* cursor  = (int*)p; p += (size_t)NN * 4;
    int* bsum    = (int*)p; p += 256 * 4;
    int* boff    = (int*)p; p += 256 * 4;
    int* csr_src = (int*)p; p += (size_t)EE * 4;
    int* start   = (int*)p; p += (BB + 1) * 4;
    float* c1 = stats + 1024;
    float* c2 = stats + 1152;

    const int nb = (NN + 255) / 256;

    // weight plane split (tiny)
    cvt_wt_planes<<<(768 * 512 + 255) / 256, 256, 0, stream>>>(W[0], Wh[0], Wl[0], 768, 512);
    cvt_wt_planes<<<(512 * 256 + 255) / 256, 256, 0, stream>>>(W[1], Wh[1], Wl[1], 512, 256);
    cvt_wt_planes<<<(256 * 128 + 255) / 256, 256, 0, stream>>>(W[2], Wh[2], Wl[2], 256, 128);

    // degree + dis + CSR
    fill_i32<<<nb, 256, 0, stream>>>(deg_i, NN, 0);
    deg_edges<<<(EE + 255) / 256, 256, 0, stream>>>(ei, deg_i);
    scan_block<<<nb, 256, 0, stream>>>(deg_i, rowptr, bsum, dis);
    scan_sums<<<1, 256, 0, stream>>>(bsum, boff, nb);
    scan_fixup<<<nb, 256, 0, stream>>>(rowptr, boff, cursor);
    fill_csr<<<(EE + 255) / 256, 256, 0, stream>>>(ei, cursor, csr_src);

    const int dims[4] = {768, 512, 256, 128};

    for (int l = 0; l < 3; ++l) {
        int K = dims[l], D = dims[l + 1];

        int nwg = (D / 128) * (MP / 128);
        if (l == 0)
            gemm_split3<0><<<nwg, 256, 0, stream>>>((const unsigned int*)x, Wh[0], Wl[0],
                                                    hw, dis, K, D);
        else
            gemm_split3<1><<<nwg, 256, 0, stream>>>(agg, Wh[l], Wl[l], hw, dis, K, D);

        int tpn = D / 8;
        int npb = 256 / tpn;
        agg_gather<<<(NN + npb - 1) / npb, 256, 0, stream>>>(hw, (float*)agg, rowptr, csr_src,
                                                             dis, bbv[l], D);

        fill_f32<<<(2 * D + 255) / 256, 256, 0, stream>>>(stats, 2 * D, 0.0f);
        bn_stats<<<dim3((D + 255) / 256, 256), 256, 0, stream>>>((const float*)agg, stats, D);
        if (l < 2) {
            size_t tot = (size_t)NN * D;
            bn_apply<<<(int)((tot + 255) / 256), 256, 0, stream>>>(agg, stats, gm[l], bt[l], D);
        } else {
            bn_coef<<<1, 128, 0, stream>>>(stats, gm[2], bt[2], c1, c2, 128);
        }
    }

    find_starts<<<nb, 256, 0, stream>>>(batch, start);
    dim3 pg(BB, PSEG);
    pool_part<<<pg, 128, 0, stream>>>((const float*)agg, start, c1, c2, part);
    pool_reduce<<<BB, 128, 0, stream>>>(part, start, pool);
    classifier_kernel<<<1, 256, 0, stream>>>(pool, Wc1, bc1, gc, bec, Wc2, bc2, out);
}

// Round 14
// 741.199 us; speedup vs baseline: 1.7218x; 1.0668x over previous
//
#include <hip/hip_runtime.h>
#include <cstddef>

#define NN 50000
#define EE 400000
#define BB 64
#define MP 50048            // padded rows: 391 * 128
#define BN_EPS 1e-5f
#define PSEG 32             // pooling segments per graph

typedef __attribute__((ext_vector_type(8))) short s16x8;
typedef __attribute__((ext_vector_type(4))) float f32x4;
typedef __attribute__((ext_vector_type(8))) _Float16 f16x8;

#define GLOAD_LDS16(g, l) __builtin_amdgcn_global_load_lds( \
    (const __attribute__((address_space(1))) void*)(g),     \
    (__attribute__((address_space(3))) void*)(l), 16, 0, 0)

// ---------------- utility ----------------
__global__ void fill_f32(float* __restrict__ p, int n, float v) {
    int i = blockIdx.x * blockDim.x + threadIdx.x;
    if (i < n) p[i] = v;
}

__global__ void fill_i32(int* __restrict__ p, int n, int v) {
    int i = blockIdx.x * blockDim.x + threadIdx.x;
    if (i < n) p[i] = v;
}

__global__ void deg_edges(const int* __restrict__ ei, int* __restrict__ deg) {
    int e = blockIdx.x * blockDim.x + threadIdx.x;
    if (e < EE) atomicAdd(&deg[ei[EE + e]], 1);
}

// W [K][N] fp32 -> two bf16 planes Wh/Wl [N][K] (hi = truncate, lo = residual)
__global__ void cvt_wt_planes(const float* __restrict__ W,
                              unsigned short* __restrict__ Wh,
                              unsigned short* __restrict__ Wl,
                              int K, int N) {
    int i = blockIdx.x * blockDim.x + threadIdx.x;
    if (i >= K * N) return;
    int k = i / N, n = i % N;
    float f = W[i];
    unsigned int fb = __float_as_uint(f);
    unsigned int hif = fb & 0xFFFF0000u;
    float lo = f - __uint_as_float(hif);
    Wh[(size_t)n * K + k] = (unsigned short)(hif >> 16);
    Wl[(size_t)n * K + k] = (unsigned short)(__float_as_uint(lo) >> 16);
}

// ---------------- CSR build (scan; rsqrt fused) ----------------
__global__ __launch_bounds__(256) void scan_block(const int* __restrict__ deg,
                                                  int* __restrict__ rowptr,
                                                  int* __restrict__ bsum,
                                                  float* __restrict__ dis) {
    __shared__ int tmp[256];
    int tid = threadIdx.x;
    int i = blockIdx.x * 256 + tid;
    int v = (i < NN) ? deg[i] : 0;
    if (i < NN) dis[i] = rsqrtf((float)v + 1.0f);
    tmp[tid] = v;
    __syncthreads();
#pragma unroll
    for (int off = 1; off < 256; off <<= 1) {
        int t = (tid >= off) ? tmp[tid - off] : 0;
        __syncthreads();
        tmp[tid] += t;
        __syncthreads();
    }
    if (i < NN) rowptr[i] = tmp[tid] - v;
    if (tid == 255) bsum[blockIdx.x] = tmp[255];
}

__global__ __launch_bounds__(256) void scan_sums(const int* __restrict__ bsum,
                                                 int* __restrict__ boff, int nb) {
    __shared__ int tmp[256];
    int tid = threadIdx.x;
    int v = (tid < nb) ? bsum[tid] : 0;
    tmp[tid] = v;
    __syncthreads();
#pragma unroll
    for (int off = 1; off < 256; off <<= 1) {
        int t = (tid >= off) ? tmp[tid - off] : 0;
        __syncthreads();
        tmp[tid] += t;
        __syncthreads();
    }
    boff[tid] = tmp[tid] - v;
}

__global__ void scan_fixup(int* __restrict__ rowptr, const int* __restrict__ boff,
                           int* __restrict__ cursor) {
    int i = blockIdx.x * blockDim.x + threadIdx.x;
    if (i < NN) {
        int v = rowptr[i] + boff[i >> 8];
        rowptr[i] = v;
        cursor[i] = v;
    }
    if (i == 0) rowptr[NN] = EE;
}

__global__ void fill_csr(const int* __restrict__ ei, int* __restrict__ cursor,
                         int* __restrict__ csr_src) {
    int e = blockIdx.x * blockDim.x + threadIdx.x;
    if (e >= EE) return;
    int s = ei[e];
    int t = ei[EE + e];
    int pos = atomicAdd(&cursor[t], 1);
    csr_src[pos] = s;
}

// ---------------- split helpers (mask/shift only — hardware-validated r5-r13) ------
// 8 fp32 values -> hi bf16 (truncate) + lo bf16 (truncated residual) planes
static __device__ __forceinline__ void split8(const float* __restrict__ f,
                                              s16x8& h, s16x8& l) {
    unsigned int hi[8], lo[8];
#pragma unroll
    for (int j = 0; j < 8; ++j) {
        unsigned int e = __float_as_uint(f[j]);
        hi[j] = e & 0xFFFF0000u;
        float lf = f[j] - __uint_as_float(hi[j]);
        lo[j] = __float_as_uint(lf);
    }
    union { s16x8 v; unsigned int u[4]; } H, L;
#pragma unroll
    for (int k = 0; k < 4; ++k) {
        H.u[k] = (hi[2 * k + 1]) | (hi[2 * k] >> 16);
        L.u[k] = (lo[2 * k + 1] & 0xFFFF0000u) | (lo[2 * k] >> 16);
    }
    h = H.v; l = L.v;
}

// ------ split-bf16 3-MFMA GEMM, dbuf + XCD swizzle + T2 LDS chunk-XOR-swizzle ------
// C[MP,N] = dis[row] * (A'[MP,K] @ W[N,K]^T), fp16 out. B pre-split bf16 planes.
// AMODE 0: A' = A (fp32 x input).
// AMODE 2: A' = relu(A*c1[k]+c2[k])  — BN affine + relu fused into the A-unpack.
template <int AMODE>
__global__ __launch_bounds__(256) void gemm_split3(const unsigned int* __restrict__ A,
                                                   const unsigned short* __restrict__ Bh,
                                                   const unsigned short* __restrict__ Bl,
                                                   _Float16* __restrict__ C,
                                                   const float* __restrict__ dis,
                                                   const float* __restrict__ c1p,
                                                   const float* __restrict__ c2p,
                                                   int K, int N) {
    __shared__ unsigned int As[2][128 * 32];     // 2 x 16 KB
    __shared__ unsigned short Bsh[2][128 * 32];  // 2 x 8 KB
    __shared__ unsigned short Bsl[2][128 * 32];  // 2 x 8 KB  (total 64 KB)
    const int tid = threadIdx.x;
    const int w  = tid >> 6;
    const int lw = tid & 63;
    const int lo = lw & 15;
    const int hi = lw >> 4;
    const int wr = w >> 1, wc = w & 1;

    // XCD-aware bijective remap (m204)
    const int nwg = gridDim.x;
    const int q = nwg >> 3, r = nwg & 7;
    int orig = blockIdx.x;
    int xcd = orig & 7, idx = orig >> 3;
    int lid = (xcd < r) ? (xcd * (q + 1) + idx) : (r * (q + 1) + (xcd - r) * q + idx);
    const int nbx = N >> 7;
    const int lbx = (nbx == 4) ? 2 : (nbx == 2 ? 1 : 0);
    const int rowBase = (lid >> lbx) * 128;
    const int colBase = (lid & (nbx - 1)) * 128;

    const int arow = w * 8 + (lw >> 3);
    const int acol = ((lw & 7) ^ (lw >> 3)) * 4;           // pre-swizzled A source chunk
    const int brow = w * 16 + (lw >> 2);
    const int bcol = ((lw & 3) ^ ((lw >> 2) & 3)) * 8;     // pre-swizzled B source chunk

    f32x4 acc[4][4];
#pragma unroll
    for (int m = 0; m < 4; ++m)
#pragma unroll
        for (int n = 0; n < 4; ++n) acc[m][n] = (f32x4){0.f, 0.f, 0.f, 0.f};

#define STAGE(buf, k0s) do {                                                        \
    _Pragma("unroll")                                                               \
    for (int i_ = 0; i_ < 4; ++i_) {                                                \
        int gr_ = rowBase + i_ * 32 + arow;                                         \
        gr_ = (gr_ < NN) ? gr_ : (NN - 1);                                          \
        GLOAD_LDS16(A + (size_t)gr_ * K + (k0s) + acol,                             \
                    (char*)&As[buf][0] + i_ * 4096 + w * 1024);                     \
    }                                                                               \
    _Pragma("unroll")                                                               \
    for (int j_ = 0; j_ < 2; ++j_) {                                                \
        int gc_ = colBase + j_ * 64 + brow;                                         \
        GLOAD_LDS16(Bh + (size_t)gc_ * K + (k0s) + bcol,                            \
                    (char*)&Bsh[buf][0] + j_ * 4096 + w * 1024);                    \
        GLOAD_LDS16(Bl + (size_t)gc_ * K + (k0s) + bcol,                            \
                    (char*)&Bsl[buf][0] + j_ * 4096 + w * 1024);                    \
    }                                                                               \
} while (0)

    STAGE(0, 0);
    asm volatile("s_waitcnt vmcnt(0)" ::: "memory");
    __builtin_amdgcn_s_barrier();

    const int nt = K >> 5;
    int cur = 0;
    for (int t = 0; t < nt; ++t) {
        if (t + 1 < nt) STAGE(cur ^ 1, (t + 1) << 5);

        // per-K-step BN coefs (fragment k-range = k0 + hi*8 .. +7, same for all m)
        float c1v[8], c2v[8];
        if (AMODE == 2) {
            int kb = (t << 5) + hi * 8;
            f32x4 a0 = *(const f32x4*)&c1p[kb];
            f32x4 a1 = *(const f32x4*)&c1p[kb + 4];
            f32x4 b0 = *(const f32x4*)&c2p[kb];
            f32x4 b1 = *(const f32x4*)&c2p[kb + 4];
#pragma unroll
            for (int j = 0; j < 4; ++j) {
                c1v[j] = a0[j]; c1v[4 + j] = a1[j];
                c2v[j] = b0[j]; c2v[4 + j] = b1[j];
            }
        }

        s16x8 ah[4], al[4], bh[4], bl[4];
#pragma unroll
        for (int m = 0; m < 4; ++m) {
            int rr = wr * 64 + m * 16 + lo;
            int c0 = ((hi * 2) ^ (rr & 7)) * 4;
            int c1 = ((hi * 2 + 1) ^ (rr & 7)) * 4;
            uint4 u0 = *(const uint4*)&As[cur][rr * 32 + c0];
            uint4 u1 = *(const uint4*)&As[cur][rr * 32 + c1];
            float f[8];
            f[0] = __uint_as_float(u0.x); f[1] = __uint_as_float(u0.y);
            f[2] = __uint_as_float(u0.z); f[3] = __uint_as_float(u0.w);
            f[4] = __uint_as_float(u1.x); f[5] = __uint_as_float(u1.y);
            f[6] = __uint_as_float(u1.z); f[7] = __uint_as_float(u1.w);
            if (AMODE == 2) {
#pragma unroll
                for (int j = 0; j < 8; ++j)
                    f[j] = fmaxf(f[j] * c1v[j] + c2v[j], 0.f);
            }
            split8(f, ah[m], al[m]);
        }
#pragma unroll
        for (int n = 0; n < 4; ++n) {
            int rr = wc * 64 + n * 16 + lo;
            int cb = (hi ^ (rr & 3)) * 8;
            bh[n] = *(const s16x8*)&Bsh[cur][rr * 32 + cb];
            bl[n] = *(const s16x8*)&Bsl[cur][rr * 32 + cb];
        }
#pragma unroll
        for (int m = 0; m < 4; ++m)
#pragma unroll
            for (int n = 0; n < 4; ++n) {
                acc[m][n] = __builtin_amdgcn_mfma_f32_16x16x32_bf16(ah[m], bh[n], acc[m][n], 0, 0, 0);
                acc[m][n] = __builtin_amdgcn_mfma_f32_16x16x32_bf16(ah[m], bl[n], acc[m][n], 0, 0, 0);
                acc[m][n] = __builtin_amdgcn_mfma_f32_16x16x32_bf16(al[m], bh[n], acc[m][n], 0, 0, 0);
            }

        asm volatile("s_waitcnt vmcnt(0)" ::: "memory");
        __builtin_amdgcn_s_barrier();
        cur ^= 1;
    }
#undef STAGE

#pragma unroll
    for (int m = 0; m < 4; ++m) {
        int row0 = rowBase + wr * 64 + m * 16 + hi * 4;
#pragma unroll
        for (int j = 0; j < 4; ++j) {
            int rr = row0 + j;
            float ds = dis[(rr < NN) ? rr : (NN - 1)];
#pragma unroll
            for (int n = 0; n < 4; ++n) {
                int col = colBase + wc * 64 + n * 16 + lo;
                C[(size_t)rr * N + col] = (_Float16)(ds * acc[m][n][j]);
            }
        }
    }
}

// ------ gather aggregation: fp16 hws in, fp32 agg out, 4-edge unroll (validated) ------
__global__ __launch_bounds__(256) void agg_gather(const _Float16* __restrict__ hws,
                                                  float* __restrict__ agg,
                                                  const int* __restrict__ rowptr,
                                                  const int* __restrict__ csr_src,
                                                  const float* __restrict__ dis,
                                                  const float* __restrict__ bias,
                                                  int D) {
    const int tpn = D >> 3;
    const int npb = 256 / tpn;
    const int local = threadIdx.x / tpn;
    const int lane = threadIdx.x % tpn;
    const int n = blockIdx.x * npb + local;
    if (n >= NN) return;
    const int dq = lane * 8;

    f16x8 sv = *(const f16x8*)&hws[(size_t)n * D + dq];
    float a[8];
#pragma unroll
    for (int j = 0; j < 8; ++j) a[j] = (float)sv[j];

    int e0 = rowptr[n], e1 = rowptr[n + 1];
    int e = e0;
    for (; e + 4 <= e1; e += 4) {
        int s0 = csr_src[e + 0];
        int s1 = csr_src[e + 1];
        int s2 = csr_src[e + 2];
        int s3 = csr_src[e + 3];
        f16x8 v0 = *(const f16x8*)&hws[(size_t)s0 * D + dq];
        f16x8 v1 = *(const f16x8*)&hws[(size_t)s1 * D + dq];
        f16x8 v2 = *(const f16x8*)&hws[(size_t)s2 * D + dq];
        f16x8 v3 = *(const f16x8*)&hws[(size_t)s3 * D + dq];
#pragma unroll
        for (int j = 0; j < 8; ++j)
            a[j] += ((float)v0[j] + (float)v1[j]) + ((float)v2[j] + (float)v3[j]);
    }
    for (; e < e1; ++e) {
        int s = csr_src[e];
        f16x8 v = *(const f16x8*)&hws[(size_t)s * D + dq];
#pragma unroll
        for (int j = 0; j < 8; ++j) a[j] += (float)v[j];
    }

    float din = dis[n];
    f32x4 o0, o1;
#pragma unroll
    for (int j = 0; j < 4; ++j) o0[j] = din * a[j] + bias[dq + j];
#pragma unroll
    for (int j = 0; j < 4; ++j) o1[j] = din * a[4 + j] + bias[dq + 4 + j];
    *(f32x4*)&agg[(size_t)n * D + dq] = o0;
    *(f32x4*)&agg[(size_t)n * D + dq + 4] = o1;
}

// ---------------- batchnorm stats (column-striped, validated) ----------------
__global__ void bn_stats(const float* __restrict__ h, float* __restrict__ stats, int D) {
    int d = blockIdx.x * blockDim.x + threadIdx.x;
    if (d >= D) return;
    float s = 0.f, ss = 0.f;
    for (int n = blockIdx.y; n < NN; n += gridDim.y) {
        float v = h[(size_t)n * D + d];
        s += v;
        ss += v * v;
    }
    atomicAdd(&stats[d], s);
    atomicAdd(&stats[D + d], ss);
}

// ---------------- per-layer BN coefficients: c1 = gamma*rstd, c2 = beta - mean*c1 ---
__global__ void bn_coef(const float* __restrict__ stats,
                        const float* __restrict__ gamma, const float* __restrict__ beta,
                        float* __restrict__ c1, float* __restrict__ c2, int D) {
    int d = blockIdx.x * blockDim.x + threadIdx.x;
    if (d >= D) return;
    float mean = stats[d] * (1.0f / NN);
    float var  = stats[D + d] * (1.0f / NN) - mean * mean;
    float r = rsqrtf(var + BN_EPS) * gamma[d];
    c1[d] = r;
    c2[d] = beta[d] - mean * r;
}

// ---------------- pooling (two-stage segmented, BN affine fused; validated) ------
__global__ void find_starts(const int* __restrict__ batch, int* __restrict__ start) {
    int n = blockIdx.x * blockDim.x + threadIdx.x;
    if (n >= NN) return;
    int bc = batch[n];
    int bp = (n == 0) ? -1 : batch[n - 1];
    for (int g = bp + 1; g <= bc; ++g) start[g] = n;
    if (n == NN - 1) {
        for (int g = bc + 1; g <= BB; ++g) start[g] = NN;
    }
}

__global__ void pool_part(const float* __restrict__ h, const int* __restrict__ start,
                          const float* __restrict__ c1, const float* __restrict__ c2,
                          float* __restrict__ part) {
    int b = blockIdx.x;
    int seg = blockIdx.y;
    int d = threadIdx.x;
    int s0 = start[b], s1 = start[b + 1];
    int len = s1 - s0;
    int a = s0 + (int)((long long)len * seg / PSEG);
    int e = s0 + (int)((long long)len * (seg + 1) / PSEG);
    float a1 = c1[d], a2 = c2[d];
    float sum = 0.f;
    float mx = -3.402823466e+38f;
    for (int n = a; n < e; ++n) {
        float v = a1 * h[(size_t)n * 128 + d] + a2;
        sum += v;
        mx = fmaxf(mx, v);
    }
    part[(size_t)(b * PSEG + seg) * 256 + d] = sum;
    part[(size_t)(b * PSEG + seg) * 256 + 128 + d] = mx;
}

__global__ void pool_reduce(const float* __restrict__ part, const int* __restrict__ start,
                            float* __restrict__ pool) {
    int b = blockIdx.x;
    int d = threadIdx.x;
    float sum = 0.f;
    float mx = -3.402823466e+38f;
    for (int s = 0; s < PSEG; ++s) {
        sum += part[(size_t)(b * PSEG + s) * 256 + d];
        mx = fmaxf(mx, part[(size_t)(b * PSEG + s) * 256 + 128 + d]);
    }
    float cnt = fmaxf((float)(start[b + 1] - start[b]), 1.0f);
    pool[b * 256 + d] = sum / cnt;
    pool[b * 256 + 128 + d] = mx;
}

// ---------------- classifier (single block, fp32) ----------------
__global__ __launch_bounds__(256) void classifier_kernel(
        const float* __restrict__ pool,
        const float* __restrict__ Wc1, const float* __restrict__ bc1,
        const float* __restrict__ gc, const float* __restrict__ bec,
        const float* __restrict__ Wc2, const float* __restrict__ bc2,
        float* __restrict__ out) {
    __shared__ float hc[64][65];
    __shared__ float cmean[64];
    __shared__ float crstd[64];
    int tid = threadIdx.x;

    for (int i = tid; i < 64 * 64; i += 256) {
        int r = i / 64, c = i % 64;
        float acc = bc1[c];
        for (int k = 0; k < 256; ++k)
            acc += pool[r * 256 + k] * Wc1[k * 64 + c];
        hc[r][c] = fmaxf(acc, 0.f);
    }
    __syncthreads();

    if (tid < 64) {
        float s = 0.f, ss = 0.f;
        for (int r = 0; r < 64; ++r) {
            float v = hc[r][tid];
            s += v;
            ss += v * v;
        }
        float m = s * (1.0f / 64.0f);
        float var = ss * (1.0f / 64.0f) - m * m;
        cmean[tid] = m;
        crstd[tid] = rsqrtf(var + BN_EPS);
    }
    __syncthreads();

    if (tid < 128) {
        int r = tid / 2, k = tid % 2;
        float acc = bc2[k];
        for (int c = 0; c < 64; ++c) {
            float v = (hc[r][c] - cmean[c]) * crstd[c] * gc[c] + bec[c];
            acc += v * Wc2[c * 2 + k];
        }
        out[r * 2 + k] = acc;
    }
}

// ---------------- launch ----------------
extern "C" void kernel_launch(void* const* d_in, const int* in_sizes, int n_in,
                              void* d_out, int out_size, void* d_ws, size_t ws_size,
                              hipStream_t stream) {
    const float* x     = (const float*)d_in[0];
    const int*   ei    = (const int*)d_in[1];
    const int*   batch = (const int*)d_in[2];
    const float* W[3]  = {(const float*)d_in[3], (const float*)d_in[7], (const float*)d_in[11]};
    const float* bbv[3] = {(const float*)d_in[4], (const float*)d_in[8], (const float*)d_in[12]};
    const float* gm[3] = {(const float*)d_in[5], (const float*)d_in[9], (const float*)d_in[13]};
    const float* bt[3] = {(const float*)d_in[6], (const float*)d_in[10], (const float*)d_in[14]};
    const float* Wc1 = (const float*)d_in[15];
    const float* bc1 = (const float*)d_in[16];
    const float* gc  = (const float*)d_in[17];
    const float* bec = (const float*)d_in[18];
    const float* Wc2 = (const float*)d_in[19];
    const float* bc2 = (const float*)d_in[20];
    float* out = (float*)d_out;

    // workspace carve-up
    char* p = (char*)d_ws;
    _Float16* hw = (_Float16*)p; p += (size_t)MP * 512 * 2;   // fp16 dis-scaled GEMM out
    float* agg = (float*)p; p += (size_t)NN * 512 * 4;        // agg f32 (gather out / gemm A in)
    unsigned short* Wh[3];
    unsigned short* Wl[3];
    Wh[0] = (unsigned short*)p; p += (size_t)512 * 768 * 2;
    Wl[0] = (unsigned short*)p; p += (size_t)512 * 768 * 2;
    Wh[1] = (unsigned short*)p; p += (size_t)256 * 512 * 2;
    Wl[1] = (unsigned short*)p; p += (size_t)256 * 512 * 2;
    Wh[2] = (unsigned short*)p; p += (size_t)128 * 256 * 2;
    Wl[2] = (unsigned short*)p; p += (size_t)128 * 256 * 2;
    float* dis   = (float*)p; p += (size_t)NN * 4;
    float* stats = (float*)p; p += 1024 * 4;
    float* c1v   = (float*)p; p += 512 * 4;
    float* c2v   = (float*)p; p += 512 * 4;
    float* pool  = (float*)p; p += (size_t)BB * 256 * 4;
    float* part  = (float*)p; p += (size_t)BB * PSEG * 256 * 4;
    int* deg_i   = (int*)p; p += (size_t)NN * 4;
    int* rowptr  = (int*)p; p += (size_t)(NN + 1) * 4;
    int* cursor  = (int*)p; p += (size_t)NN * 4;
    int* bsum    = (int*)p; p += 256 * 4;
    int* boff    = (int*)p; p += 256 * 4;
    int* csr_src = (int*)p; p += (size_t)EE * 4;
    int* start   = (int*)p; p += (BB + 1) * 4;

    const int nb = (NN + 255) / 256;

    // weight plane split (tiny)
    cvt_wt_planes<<<(768 * 512 + 255) / 256, 256, 0, stream>>>(W[0], Wh[0], Wl[0], 768, 512);
    cvt_wt_planes<<<(512 * 256 + 255) / 256, 256, 0, stream>>>(W[1], Wh[1], Wl[1], 512, 256);
    cvt_wt_planes<<<(256 * 128 + 255) / 256, 256, 0, stream>>>(W[2], Wh[2], Wl[2], 256, 128);

    // degree + dis + CSR
    fill_i32<<<nb, 256, 0, stream>>>(deg_i, NN, 0);
    deg_edges<<<(EE + 255) / 256, 256, 0, stream>>>(ei, deg_i);
    scan_block<<<nb, 256, 0, stream>>>(deg_i, rowptr, bsum, dis);
    scan_sums<<<1, 256, 0, stream>>>(bsum, boff, nb);
    scan_fixup<<<nb, 256, 0, stream>>>(rowptr, boff, cursor);
    fill_csr<<<(EE + 255) / 256, 256, 0, stream>>>(ei, cursor, csr_src);

    const int dims[4] = {768, 512, 256, 128};

    for (int l = 0; l < 3; ++l) {
        int K = dims[l], D = dims[l + 1];

        int nwg = (D / 128) * (MP / 128);
        if (l == 0)
            gemm_split3<0><<<nwg, 256, 0, stream>>>((const unsigned int*)x, Wh[0], Wl[0],
                                                    hw, dis, nullptr, nullptr, K, D);
        else
            gemm_split3<2><<<nwg, 256, 0, stream>>>((const unsigned int*)agg, Wh[l], Wl[l],
                                                    hw, dis, c1v, c2v, K, D);

        int tpn = D / 8;
        int npb = 256 / tpn;
        agg_gather<<<(NN + npb - 1) / npb, 256, 0, stream>>>(hw, agg, rowptr, csr_src,
                                                             dis, bbv[l], D);

        fill_f32<<<(2 * D + 255) / 256, 256, 0, stream>>>(stats, 2 * D, 0.0f);
        bn_stats<<<dim3((D + 255) / 256, 256), 256, 0, stream>>>(agg, stats, D);
        bn_coef<<<1, D, 0, stream>>>(stats, gm[l], bt[l], c1v, c2v, D);
    }

    find_starts<<<nb, 256, 0, stream>>>(batch, start);
    dim3 pg(BB, PSEG);
    pool_part<<<pg, 128, 0, stream>>>(agg, start, c1v, c2v, part);
    pool_reduce<<<BB, 128, 0, stream>>>(part, start, pool);
    classifier_kernel<<<1, 256, 0, stream>>>(pool, Wc1, bc1, gc, bec, Wc2, bc2, out);
}